// Round 1
// baseline (10904.875 us; speedup 1.0000x reference)
//
#include <hip/hip_runtime.h>
#include <math.h>

// ---------------------------------------------------------------------------
// EmergencyGNNEnhanced: encoder (32->256->128) -> 3x GCN (->64) -> edge MLP.
// All fp32. CSR built on-device each call (graph-capture safe, same work).
// Aggregation: agg[v] = dinv[v]*(sum_{u->v} y[u] + y[v]),  y = dinv .* (h@W).
// Workspace layout (213 MB total):
//   h1   [N,256] = 25.6M f  (aliased later as e1 [EL,128] = 25.6M f)
//   h128 [N,128] = 12.8M f  (aliased later as e2 [EL,64]  = 12.8M f)
//   y    [N,64], h64 [N,64], CSR (col,row_ptr,cursor,cnt,dinv,partial)
// ---------------------------------------------------------------------------

#define N_NODES 100000
#define N_EDGES 1600000
#define N_EL    200000
#define SCAN_NB 196          // ceil(100000/512)

// ---------------- CSR build ----------------
__global__ __launch_bounds__(256) void deg_kernel(const int* __restrict__ ei, int* __restrict__ cnt) {
    int e = blockIdx.x * 256 + threadIdx.x;
    if (e < N_EDGES) atomicAdd(&cnt[ei[N_EDGES + e]], 1);
}

__global__ __launch_bounds__(256) void dinv_kernel(const int* __restrict__ cnt, float* __restrict__ dinv) {
    int i = blockIdx.x * 256 + threadIdx.x;
    if (i < N_NODES) dinv[i] = rsqrtf((float)(cnt[i] + 1));   // +1 self loop
}

__global__ __launch_bounds__(256) void scan1(const int* __restrict__ cnt, int* __restrict__ partial) {
    __shared__ int sm[256];
    int b = blockIdx.x, t = threadIdx.x;
    int base = b * 512;
    int v = 0;
    if (base + t < N_NODES)       v += cnt[base + t];
    if (base + 256 + t < N_NODES) v += cnt[base + 256 + t];
    sm[t] = v; __syncthreads();
    for (int s = 128; s > 0; s >>= 1) { if (t < s) sm[t] += sm[t + s]; __syncthreads(); }
    if (t == 0) partial[b] = sm[0];
}

__global__ __launch_bounds__(256) void scan2(int* __restrict__ partial, int* __restrict__ row_ptr) {
    __shared__ int sm[256];
    int t = threadIdx.x;
    int v = (t < SCAN_NB) ? partial[t] : 0;
    sm[t] = v; __syncthreads();
    for (int s = 1; s < 256; s <<= 1) {
        int add = (t >= s) ? sm[t - s] : 0;
        __syncthreads();
        sm[t] += add;
        __syncthreads();
    }
    if (t < SCAN_NB) partial[t] = sm[t] - v;          // exclusive
    if (t == 0) row_ptr[N_NODES] = N_EDGES;
}

__global__ __launch_bounds__(256) void scan3(const int* __restrict__ cnt, const int* __restrict__ partial,
                                             int* __restrict__ row_ptr, int* __restrict__ cursor) {
    __shared__ int sm[256];
    int b = blockIdx.x, t = threadIdx.x;
    int base = b * 512;
    int i0 = base + 2 * t, i1 = i0 + 1;
    int e0 = (i0 < N_NODES) ? cnt[i0] : 0;
    int e1 = (i1 < N_NODES) ? cnt[i1] : 0;
    int s2 = e0 + e1;
    sm[t] = s2; __syncthreads();
    for (int s = 1; s < 256; s <<= 1) {
        int add = (t >= s) ? sm[t - s] : 0;
        __syncthreads();
        sm[t] += add;
        __syncthreads();
    }
    int excl = sm[t] - s2 + partial[b];
    if (i0 < N_NODES) { row_ptr[i0] = excl;      cursor[i0] = excl; }
    if (i1 < N_NODES) { row_ptr[i1] = excl + e0; cursor[i1] = excl + e0; }
}

__global__ __launch_bounds__(256) void fill_kernel(const int* __restrict__ ei, int* __restrict__ cursor,
                                                   int* __restrict__ col) {
    int e = blockIdx.x * 256 + threadIdx.x;
    if (e < N_EDGES) {
        int d = ei[N_EDGES + e];
        int p = atomicAdd(&cursor[d], 1);
        col[p] = ei[e];
    }
}

// ---------------- Generic tiled GEMM: C = epilogue(A @ W) ----------------
// A: [M,KTOT] row-major (or gathered concat h64[a]||h64[b] when GATHER)
// W: [KTOT,NC] row-major. Block: 64 rows x NT cols. 256 threads.
template<int NT, int NC, int KTOT, bool HAS_BIAS, bool RELU, bool SCALE, bool GATHER>
__global__ __launch_bounds__(256) void gemm_kernel(
    const float* __restrict__ A, const float* __restrict__ W,
    const float* __restrict__ bias, float* __restrict__ C,
    const float* __restrict__ dinv, const int* __restrict__ gidx, int M)
{
    constexpr int KB  = 32;
    constexpr int CT  = NT / 4;        // threads along columns
    constexpr int RT  = 256 / CT;      // threads along rows
    constexpr int RPT = 64 / RT;       // rows per thread (8 for NT=128, 4 for NT=64)

    __shared__ float As[KB][72];       // transposed [k][row]; 72 = 64+8 pad (16B aligned rows)
    __shared__ float Ws[KB][NT];

    int t  = threadIdx.x;
    int m0 = blockIdx.x * 64;
    int c0 = blockIdx.y * NT;
    int tx = t % CT, ty = t / CT;

    float acc[RPT][4];
    #pragma unroll
    for (int r = 0; r < RPT; ++r)
        #pragma unroll
        for (int c = 0; c < 4; ++c) acc[r][c] = 0.f;

    for (int k0 = 0; k0 < KTOT; k0 += KB) {
        // stage A tile (64 x 32), transposed into LDS
        #pragma unroll
        for (int i = 0; i < 8; ++i) {
            int idx = t + i * 256;
            int row = idx >> 5, kk = idx & 31;
            int gr = m0 + row, gk = k0 + kk;
            float v = 0.f;
            if (gr < M) {
                if (GATHER) {
                    int node = (gk < 64) ? gidx[gr] : gidx[N_EL + gr];
                    v = A[(size_t)node * 64 + (gk & 63)];
                } else {
                    v = A[(size_t)gr * KTOT + gk];
                }
            }
            As[kk][row] = v;
        }
        // stage W tile (32 x NT)
        #pragma unroll
        for (int i = 0; i < KB * NT / 256; ++i) {
            int idx = t + i * 256;
            int kk = idx / NT, cc = idx % NT;
            Ws[kk][cc] = W[(size_t)(k0 + kk) * NC + c0 + cc];
        }
        __syncthreads();

        for (int kk = 0; kk < KB; ++kk) {
            float4 wv = *(const float4*)&Ws[kk][tx * 4];
            float av[RPT];
            #pragma unroll
            for (int j = 0; j < RPT / 4; ++j) {
                float4 a4 = *(const float4*)&As[kk][ty * RPT + j * 4];
                av[j * 4 + 0] = a4.x; av[j * 4 + 1] = a4.y;
                av[j * 4 + 2] = a4.z; av[j * 4 + 3] = a4.w;
            }
            #pragma unroll
            for (int r = 0; r < RPT; ++r) {
                acc[r][0] += av[r] * wv.x;
                acc[r][1] += av[r] * wv.y;
                acc[r][2] += av[r] * wv.z;
                acc[r][3] += av[r] * wv.w;
            }
        }
        __syncthreads();
    }

    float4 bv = make_float4(0.f, 0.f, 0.f, 0.f);
    if (HAS_BIAS) bv = *(const float4*)&bias[c0 + tx * 4];

    #pragma unroll
    for (int r = 0; r < RPT; ++r) {
        int gr = m0 + ty * RPT + r;
        if (gr < M) {
            float4 v;
            v.x = acc[r][0] + bv.x; v.y = acc[r][1] + bv.y;
            v.z = acc[r][2] + bv.z; v.w = acc[r][3] + bv.w;
            if (RELU) {
                v.x = fmaxf(v.x, 0.f); v.y = fmaxf(v.y, 0.f);
                v.z = fmaxf(v.z, 0.f); v.w = fmaxf(v.w, 0.f);
            }
            if (SCALE) {
                float s = dinv[gr];
                v.x *= s; v.y *= s; v.z *= s; v.w *= s;
            }
            *(float4*)&C[(size_t)gr * NC + c0 + tx * 4] = v;
        }
    }
}

// ---------------- CSR aggregation: one wave per node, lane = feature ----------------
__global__ __launch_bounds__(256) void agg_kernel(
    const float* __restrict__ y, const int* __restrict__ row_ptr, const int* __restrict__ col,
    const float* __restrict__ dinv, const float* __restrict__ bias,
    float* __restrict__ h, int residual)
{
    int v = blockIdx.x * 4 + (threadIdx.x >> 6);
    int lane = threadIdx.x & 63;
    if (v >= N_NODES) return;
    float acc = y[(size_t)v * 64 + lane];           // self loop
    int s = row_ptr[v], e = row_ptr[v + 1];
    int i = s;
    for (; i + 3 < e; i += 4) {
        int u0 = col[i], u1 = col[i + 1], u2 = col[i + 2], u3 = col[i + 3];
        float f0 = y[(size_t)u0 * 64 + lane];
        float f1 = y[(size_t)u1 * 64 + lane];
        float f2 = y[(size_t)u2 * 64 + lane];
        float f3 = y[(size_t)u3 * 64 + lane];
        acc += f0 + f1 + f2 + f3;
    }
    for (; i < e; ++i) acc += y[(size_t)col[i] * 64 + lane];
    float val = fmaxf(dinv[v] * acc + bias[lane], 0.f);
    size_t o = (size_t)v * 64 + lane;
    if (residual) h[o] += val; else h[o] = val;
}

// ---------------- final edge layer: dot(e2[p], w3) + b3 -> sigmoid ----------------
__global__ __launch_bounds__(256) void ep3_kernel(const float* __restrict__ e2, const float* __restrict__ w3,
                                                  const float* __restrict__ b3, float* __restrict__ out) {
    int p = blockIdx.x * 4 + (threadIdx.x >> 6);
    int lane = threadIdx.x & 63;
    if (p >= N_EL) return;
    float v = e2[(size_t)p * 64 + lane] * w3[lane];
    v += __shfl_xor(v, 32);
    v += __shfl_xor(v, 16);
    v += __shfl_xor(v, 8);
    v += __shfl_xor(v, 4);
    v += __shfl_xor(v, 2);
    v += __shfl_xor(v, 1);
    if (lane == 0) out[p] = 1.f / (1.f + expf(-(v + b3[0])));
}

extern "C" void kernel_launch(void* const* d_in, const int* in_sizes, int n_in,
                              void* d_out, int out_size, void* d_ws, size_t ws_size,
                              hipStream_t stream) {
    const float* x       = (const float*)d_in[0];
    const int*   ei      = (const int*)d_in[1];
    const int*   eli     = (const int*)d_in[2];
    const float* enc_w1  = (const float*)d_in[3];
    const float* enc_b1  = (const float*)d_in[4];
    const float* enc_w2  = (const float*)d_in[5];
    const float* enc_b2  = (const float*)d_in[6];
    const float* conv_w0 = (const float*)d_in[7];
    const float* conv_b0 = (const float*)d_in[8];
    const float* conv_w1 = (const float*)d_in[9];
    const float* conv_b1 = (const float*)d_in[10];
    const float* conv_w2 = (const float*)d_in[11];
    const float* conv_b2 = (const float*)d_in[12];
    const float* ep_w1   = (const float*)d_in[13];
    const float* ep_b1   = (const float*)d_in[14];
    const float* ep_w2   = (const float*)d_in[15];
    const float* ep_b2   = (const float*)d_in[16];
    const float* ep_w3   = (const float*)d_in[17];
    const float* ep_b3   = (const float*)d_in[18];
    float* out = (float*)d_out;

    float* fws     = (float*)d_ws;
    float* h1      = fws;                      // 25,600,000 f  (alias: e1)
    float* h128    = fws + 25600000;           // 12,800,000 f  (alias: e2)
    float* yb      = fws + 38400000;           //  6,400,000 f
    float* h64     = fws + 44800000;           //  6,400,000 f
    int*   col     = (int*)(fws + 51200000);   //  1,600,000 i
    int*   row_ptr = col + 1600000;            //    100,001 i (padded)
    int*   cursor  = row_ptr + 100032;         //    100,000 i
    int*   cnt     = cursor + 100000;          //    100,000 i
    float* dinvp   = (float*)(cnt + 100000);   //    100,000 f
    int*   partial = (int*)(dinvp + 100000);   //        256 i
    float* e1 = h1;
    float* e2 = h128;

    // ---- CSR build ----
    hipMemsetAsync(cnt, 0, N_NODES * sizeof(int), stream);
    deg_kernel <<<(N_EDGES + 255) / 256, 256, 0, stream>>>(ei, cnt);
    dinv_kernel<<<(N_NODES + 255) / 256, 256, 0, stream>>>(cnt, dinvp);
    scan1<<<SCAN_NB, 256, 0, stream>>>(cnt, partial);
    scan2<<<1, 256, 0, stream>>>(partial, row_ptr);
    scan3<<<SCAN_NB, 256, 0, stream>>>(cnt, partial, row_ptr, cursor);
    fill_kernel<<<(N_EDGES + 255) / 256, 256, 0, stream>>>(ei, cursor, col);

    const int GBN = (N_NODES + 63) / 64;   // 1563
    const int GBE = N_EL / 64;             // 3125

    // ---- encoder ----
    gemm_kernel<128, 256,  32, true,  true,  false, false><<<dim3(GBN, 2), 256, 0, stream>>>(x,    enc_w1, enc_b1, h1,   nullptr, nullptr, N_NODES);
    gemm_kernel<128, 128, 256, true,  true,  false, false><<<dim3(GBN, 1), 256, 0, stream>>>(h1,   enc_w2, enc_b2, h128, nullptr, nullptr, N_NODES);

    // ---- GCN layer 0: 128 -> 64, no residual ----
    gemm_kernel< 64,  64, 128, false, false, true,  false><<<dim3(GBN, 1), 256, 0, stream>>>(h128, conv_w0, nullptr, yb,  dinvp,  nullptr, N_NODES);
    agg_kernel<<<(N_NODES + 3) / 4, 256, 0, stream>>>(yb, row_ptr, col, dinvp, conv_b0, h64, 0);

    // ---- GCN layer 1: 64 -> 64, residual (in-place safe: each wave touches own row) ----
    gemm_kernel< 64,  64,  64, false, false, true,  false><<<dim3(GBN, 1), 256, 0, stream>>>(h64,  conv_w1, nullptr, yb,  dinvp,  nullptr, N_NODES);
    agg_kernel<<<(N_NODES + 3) / 4, 256, 0, stream>>>(yb, row_ptr, col, dinvp, conv_b1, h64, 1);

    // ---- GCN layer 2 ----
    gemm_kernel< 64,  64,  64, false, false, true,  false><<<dim3(GBN, 1), 256, 0, stream>>>(h64,  conv_w2, nullptr, yb,  dinvp,  nullptr, N_NODES);
    agg_kernel<<<(N_NODES + 3) / 4, 256, 0, stream>>>(yb, row_ptr, col, dinvp, conv_b2, h64, 1);

    // ---- edge predictor ----
    gemm_kernel<128, 128, 128, true,  true,  false, true ><<<dim3(GBE, 1), 256, 0, stream>>>(h64,  ep_w1, ep_b1, e1, nullptr, eli, N_EL);
    gemm_kernel< 64,  64, 128, true,  true,  false, false><<<dim3(GBE, 1), 256, 0, stream>>>(e1,   ep_w2, ep_b2, e2, nullptr, nullptr, N_EL);
    ep3_kernel<<<(N_EL + 3) / 4, 256, 0, stream>>>(e2, ep_w3, ep_b3, out);
}

// Round 2
// 3051.361 us; speedup vs baseline: 3.5738x; 3.5738x over previous
//
#include <hip/hip_runtime.h>
#include <math.h>

// ---------------------------------------------------------------------------
// EmergencyGNNEnhanced: encoder (32->256->128) -> 3x GCN (->64) -> edge MLP.
// All fp32. CSR built on-device each call (graph-capture safe, same work).
// Aggregation: agg[v] = dinv[v]*(sum_{u->v} y[u] + y[v]),  y = dinv .* (h@W).
//
// R1 fix: the previous 64x128 gemm tile (acc[8][4] + av[8]) was unroll-
// pipelined into 256 VGPRs + scratch spill (16.5 GB/dispatch fetch, VALUBusy
// 1.2%). New gemm: uniform 64x64 tile, 4x4 per-thread register tile,
// __launch_bounds__(256,4) caps at 128 VGPRs so the scheduler cannot spill.
// ---------------------------------------------------------------------------

#define N_NODES 100000
#define N_EDGES 1600000
#define N_EL    200000
#define SCAN_NB 196          // ceil(100000/512)

// ---------------- CSR build ----------------
__global__ __launch_bounds__(256) void deg_kernel(const int* __restrict__ ei, int* __restrict__ cnt) {
    int e = blockIdx.x * 256 + threadIdx.x;
    if (e < N_EDGES) atomicAdd(&cnt[ei[N_EDGES + e]], 1);
}

__global__ __launch_bounds__(256) void dinv_kernel(const int* __restrict__ cnt, float* __restrict__ dinv) {
    int i = blockIdx.x * 256 + threadIdx.x;
    if (i < N_NODES) dinv[i] = rsqrtf((float)(cnt[i] + 1));   // +1 self loop
}

__global__ __launch_bounds__(256) void scan1(const int* __restrict__ cnt, int* __restrict__ partial) {
    __shared__ int sm[256];
    int b = blockIdx.x, t = threadIdx.x;
    int base = b * 512;
    int v = 0;
    if (base + t < N_NODES)       v += cnt[base + t];
    if (base + 256 + t < N_NODES) v += cnt[base + 256 + t];
    sm[t] = v; __syncthreads();
    for (int s = 128; s > 0; s >>= 1) { if (t < s) sm[t] += sm[t + s]; __syncthreads(); }
    if (t == 0) partial[b] = sm[0];
}

__global__ __launch_bounds__(256) void scan2(int* __restrict__ partial, int* __restrict__ row_ptr) {
    __shared__ int sm[256];
    int t = threadIdx.x;
    int v = (t < SCAN_NB) ? partial[t] : 0;
    sm[t] = v; __syncthreads();
    for (int s = 1; s < 256; s <<= 1) {
        int add = (t >= s) ? sm[t - s] : 0;
        __syncthreads();
        sm[t] += add;
        __syncthreads();
    }
    if (t < SCAN_NB) partial[t] = sm[t] - v;          // exclusive
    if (t == 0) row_ptr[N_NODES] = N_EDGES;
}

__global__ __launch_bounds__(256) void scan3(const int* __restrict__ cnt, const int* __restrict__ partial,
                                             int* __restrict__ row_ptr, int* __restrict__ cursor) {
    __shared__ int sm[256];
    int b = blockIdx.x, t = threadIdx.x;
    int base = b * 512;
    int i0 = base + 2 * t, i1 = i0 + 1;
    int e0 = (i0 < N_NODES) ? cnt[i0] : 0;
    int e1 = (i1 < N_NODES) ? cnt[i1] : 0;
    int s2 = e0 + e1;
    sm[t] = s2; __syncthreads();
    for (int s = 1; s < 256; s <<= 1) {
        int add = (t >= s) ? sm[t - s] : 0;
        __syncthreads();
        sm[t] += add;
        __syncthreads();
    }
    int excl = sm[t] - s2 + partial[b];
    if (i0 < N_NODES) { row_ptr[i0] = excl;      cursor[i0] = excl; }
    if (i1 < N_NODES) { row_ptr[i1] = excl + e0; cursor[i1] = excl + e0; }
}

__global__ __launch_bounds__(256) void fill_kernel(const int* __restrict__ ei, int* __restrict__ cursor,
                                                   int* __restrict__ col) {
    int e = blockIdx.x * 256 + threadIdx.x;
    if (e < N_EDGES) {
        int d = ei[N_EDGES + e];
        int p = atomicAdd(&cursor[d], 1);
        col[p] = ei[e];
    }
}

// ---------------- Tiled GEMM: C = epilogue(A @ W) ----------------
// Tile: 64 rows x 64 cols, 256 threads, each thread a 4x4 register tile.
// grid.y covers NC/64 column panels. A: [M,KTOT] row-major (or gathered
// concat h64[a]||h64[b] when GATHER). W: [KTOT,NC] row-major.
// __launch_bounds__(256,4): cap 128 VGPR (4 waves/SIMD); ~50 live regs, so
// the cap restrains unroll-pipelining without inducing spill.
template<int NC, int KTOT, bool HAS_BIAS, bool RELU, bool SCALE, bool GATHER>
__global__ __launch_bounds__(256, 4) void gemm_kernel(
    const float* __restrict__ A, const float* __restrict__ W,
    const float* __restrict__ bias, float* __restrict__ C,
    const float* __restrict__ dinv, const int* __restrict__ gidx, int M)
{
    constexpr int KB = 32;

    __shared__ float As[KB][68];   // transposed [k][row]; 68 = 64+4 (keeps float4 align)
    __shared__ float Ws[KB][64];

    int t  = threadIdx.x;
    int m0 = blockIdx.x * 64;
    int c0 = blockIdx.y * 64;
    int tx = t & 15;               // col group: 16 x 4 cols
    int ty = t >> 4;               // row group: 16 x 4 rows

    float acc[4][4];
    #pragma unroll
    for (int r = 0; r < 4; ++r)
        #pragma unroll
        for (int c = 0; c < 4; ++c) acc[r][c] = 0.f;

    for (int k0 = 0; k0 < KTOT; k0 += KB) {
        // stage A tile (64 rows x 32 k), transposed into LDS
        #pragma unroll
        for (int i = 0; i < 8; ++i) {
            int idx = t + i * 256;
            int row = idx >> 5, kk = idx & 31;
            int gr = m0 + row, gk = k0 + kk;
            float v = 0.f;
            if (gr < M) {
                if (GATHER) {
                    int node = (gk < 64) ? gidx[gr] : gidx[N_EL + gr];
                    v = A[(size_t)node * 64 + (gk & 63)];
                } else {
                    v = A[(size_t)gr * KTOT + gk];
                }
            }
            As[kk][row] = v;
        }
        // stage W tile (32 k x 64 cols)
        #pragma unroll
        for (int i = 0; i < 8; ++i) {
            int idx = t + i * 256;
            int kk = idx >> 6, cc = idx & 63;
            Ws[kk][cc] = W[(size_t)(k0 + kk) * NC + c0 + cc];
        }
        __syncthreads();

        for (int kk = 0; kk < KB; ++kk) {
            float4 a4 = *(const float4*)&As[kk][ty * 4];
            float4 w4 = *(const float4*)&Ws[kk][tx * 4];
            acc[0][0] += a4.x * w4.x; acc[0][1] += a4.x * w4.y;
            acc[0][2] += a4.x * w4.z; acc[0][3] += a4.x * w4.w;
            acc[1][0] += a4.y * w4.x; acc[1][1] += a4.y * w4.y;
            acc[1][2] += a4.y * w4.z; acc[1][3] += a4.y * w4.w;
            acc[2][0] += a4.z * w4.x; acc[2][1] += a4.z * w4.y;
            acc[2][2] += a4.z * w4.z; acc[2][3] += a4.z * w4.w;
            acc[3][0] += a4.w * w4.x; acc[3][1] += a4.w * w4.y;
            acc[3][2] += a4.w * w4.z; acc[3][3] += a4.w * w4.w;
        }
        __syncthreads();
    }

    float4 bv = make_float4(0.f, 0.f, 0.f, 0.f);
    if (HAS_BIAS) bv = *(const float4*)&bias[c0 + tx * 4];

    #pragma unroll
    for (int r = 0; r < 4; ++r) {
        int gr = m0 + ty * 4 + r;
        if (gr < M) {
            float4 v;
            v.x = acc[r][0] + bv.x; v.y = acc[r][1] + bv.y;
            v.z = acc[r][2] + bv.z; v.w = acc[r][3] + bv.w;
            if (RELU) {
                v.x = fmaxf(v.x, 0.f); v.y = fmaxf(v.y, 0.f);
                v.z = fmaxf(v.z, 0.f); v.w = fmaxf(v.w, 0.f);
            }
            if (SCALE) {
                float s = dinv[gr];
                v.x *= s; v.y *= s; v.z *= s; v.w *= s;
            }
            *(float4*)&C[(size_t)gr * NC + c0 + tx * 4] = v;
        }
    }
}

// ---------------- CSR aggregation: one wave per node, lane = feature ----------------
__global__ __launch_bounds__(256) void agg_kernel(
    const float* __restrict__ y, const int* __restrict__ row_ptr, const int* __restrict__ col,
    const float* __restrict__ dinv, const float* __restrict__ bias,
    float* __restrict__ h, int residual)
{
    int v = blockIdx.x * 4 + (threadIdx.x >> 6);
    int lane = threadIdx.x & 63;
    if (v >= N_NODES) return;
    float acc = y[(size_t)v * 64 + lane];           // self loop
    int s = row_ptr[v], e = row_ptr[v + 1];
    int i = s;
    for (; i + 3 < e; i += 4) {
        int u0 = col[i], u1 = col[i + 1], u2 = col[i + 2], u3 = col[i + 3];
        float f0 = y[(size_t)u0 * 64 + lane];
        float f1 = y[(size_t)u1 * 64 + lane];
        float f2 = y[(size_t)u2 * 64 + lane];
        float f3 = y[(size_t)u3 * 64 + lane];
        acc += f0 + f1 + f2 + f3;
    }
    for (; i < e; ++i) acc += y[(size_t)col[i] * 64 + lane];
    float val = fmaxf(dinv[v] * acc + bias[lane], 0.f);
    size_t o = (size_t)v * 64 + lane;
    if (residual) h[o] += val; else h[o] = val;
}

// ---------------- final edge layer: dot(e2[p], w3) + b3 -> sigmoid ----------------
__global__ __launch_bounds__(256) void ep3_kernel(const float* __restrict__ e2, const float* __restrict__ w3,
                                                  const float* __restrict__ b3, float* __restrict__ out) {
    int p = blockIdx.x * 4 + (threadIdx.x >> 6);
    int lane = threadIdx.x & 63;
    if (p >= N_EL) return;
    float v = e2[(size_t)p * 64 + lane] * w3[lane];
    v += __shfl_xor(v, 32);
    v += __shfl_xor(v, 16);
    v += __shfl_xor(v, 8);
    v += __shfl_xor(v, 4);
    v += __shfl_xor(v, 2);
    v += __shfl_xor(v, 1);
    if (lane == 0) out[p] = 1.f / (1.f + expf(-(v + b3[0])));
}

extern "C" void kernel_launch(void* const* d_in, const int* in_sizes, int n_in,
                              void* d_out, int out_size, void* d_ws, size_t ws_size,
                              hipStream_t stream) {
    const float* x       = (const float*)d_in[0];
    const int*   ei      = (const int*)d_in[1];
    const int*   eli     = (const int*)d_in[2];
    const float* enc_w1  = (const float*)d_in[3];
    const float* enc_b1  = (const float*)d_in[4];
    const float* enc_w2  = (const float*)d_in[5];
    const float* enc_b2  = (const float*)d_in[6];
    const float* conv_w0 = (const float*)d_in[7];
    const float* conv_b0 = (const float*)d_in[8];
    const float* conv_w1 = (const float*)d_in[9];
    const float* conv_b1 = (const float*)d_in[10];
    const float* conv_w2 = (const float*)d_in[11];
    const float* conv_b2 = (const float*)d_in[12];
    const float* ep_w1   = (const float*)d_in[13];
    const float* ep_b1   = (const float*)d_in[14];
    const float* ep_w2   = (const float*)d_in[15];
    const float* ep_b2   = (const float*)d_in[16];
    const float* ep_w3   = (const float*)d_in[17];
    const float* ep_b3   = (const float*)d_in[18];
    float* out = (float*)d_out;

    float* fws     = (float*)d_ws;
    float* h1      = fws;                      // 25,600,000 f  (alias: e1)
    float* h128    = fws + 25600000;           // 12,800,000 f  (alias: e2)
    float* yb      = fws + 38400000;           //  6,400,000 f
    float* h64     = fws + 44800000;           //  6,400,000 f
    int*   col     = (int*)(fws + 51200000);   //  1,600,000 i
    int*   row_ptr = col + 1600000;            //    100,001 i (padded)
    int*   cursor  = row_ptr + 100032;         //    100,000 i
    int*   cnt     = cursor + 100000;          //    100,000 i
    float* dinvp   = (float*)(cnt + 100000);   //    100,000 f
    int*   partial = (int*)(dinvp + 100000);   //        256 i
    float* e1 = h1;
    float* e2 = h128;

    // ---- CSR build ----
    hipMemsetAsync(cnt, 0, N_NODES * sizeof(int), stream);
    deg_kernel <<<(N_EDGES + 255) / 256, 256, 0, stream>>>(ei, cnt);
    dinv_kernel<<<(N_NODES + 255) / 256, 256, 0, stream>>>(cnt, dinvp);
    scan1<<<SCAN_NB, 256, 0, stream>>>(cnt, partial);
    scan2<<<1, 256, 0, stream>>>(partial, row_ptr);
    scan3<<<SCAN_NB, 256, 0, stream>>>(cnt, partial, row_ptr, cursor);
    fill_kernel<<<(N_EDGES + 255) / 256, 256, 0, stream>>>(ei, cursor, col);

    const int GBN = (N_NODES + 63) / 64;   // 1563
    const int GBE = N_EL / 64;             // 3125

    // ---- encoder ----
    gemm_kernel<256,  32, true,  true,  false, false><<<dim3(GBN, 4), 256, 0, stream>>>(x,    enc_w1, enc_b1, h1,   nullptr, nullptr, N_NODES);
    gemm_kernel<128, 256, true,  true,  false, false><<<dim3(GBN, 2), 256, 0, stream>>>(h1,   enc_w2, enc_b2, h128, nullptr, nullptr, N_NODES);

    // ---- GCN layer 0: 128 -> 64, no residual ----
    gemm_kernel< 64, 128, false, false, true,  false><<<dim3(GBN, 1), 256, 0, stream>>>(h128, conv_w0, nullptr, yb,  dinvp,  nullptr, N_NODES);
    agg_kernel<<<(N_NODES + 3) / 4, 256, 0, stream>>>(yb, row_ptr, col, dinvp, conv_b0, h64, 0);

    // ---- GCN layer 1: 64 -> 64, residual (in-place safe: each wave touches own row) ----
    gemm_kernel< 64,  64, false, false, true,  false><<<dim3(GBN, 1), 256, 0, stream>>>(h64,  conv_w1, nullptr, yb,  dinvp,  nullptr, N_NODES);
    agg_kernel<<<(N_NODES + 3) / 4, 256, 0, stream>>>(yb, row_ptr, col, dinvp, conv_b1, h64, 1);

    // ---- GCN layer 2 ----
    gemm_kernel< 64,  64, false, false, true,  false><<<dim3(GBN, 1), 256, 0, stream>>>(h64,  conv_w2, nullptr, yb,  dinvp,  nullptr, N_NODES);
    agg_kernel<<<(N_NODES + 3) / 4, 256, 0, stream>>>(yb, row_ptr, col, dinvp, conv_b2, h64, 1);

    // ---- edge predictor ----
    gemm_kernel<128, 128, true,  true,  false, true ><<<dim3(GBE, 2), 256, 0, stream>>>(h64,  ep_w1, ep_b1, e1, nullptr, eli, N_EL);
    gemm_kernel< 64, 128, true,  true,  false, false><<<dim3(GBE, 1), 256, 0, stream>>>(e1,   ep_w2, ep_b2, e2, nullptr, nullptr, N_EL);
    ep3_kernel<<<(N_EL + 3) / 4, 256, 0, stream>>>(e2, ep_w3, ep_b3, out);
}

// Round 3
// 895.190 us; speedup vs baseline: 12.1816x; 3.4086x over previous
//
#include <hip/hip_runtime.h>
#include <math.h>

// ---------------------------------------------------------------------------
// EmergencyGNNEnhanced: encoder (32->256->128) -> 3x GCN (->64) -> edge MLP.
// All fp32. CSR built on-device each call (graph-capture safe, same work).
// Aggregation: agg[v] = dinv[v]*(sum_{u->v} y[u] + y[v]),  y = dinv .* (h@W).
//
// R2 postmortem: one gemm instantiation (VALU-time fingerprint => enc1) eats
// 2085us/3051us with 7.8GB of in-window HBM traffic it has no business doing.
// R3: (a) every gemm gets a DISTINCT kernel name so rocprof identifies the
// culprit unambiguously; (b) enc1 rewritten weight-stationary (W in LDS once,
// no K-loop barriers, rows in registers, float4 everywhere); (c) float4
// staging loads in the shared tiled-gemm body.
// ---------------------------------------------------------------------------

#define N_NODES 100000
#define N_EDGES 1600000
#define N_EL    200000
#define SCAN_NB 196          // ceil(100000/512)

// ---------------- CSR build ----------------
__global__ __launch_bounds__(256) void deg_kernel(const int* __restrict__ ei, int* __restrict__ cnt) {
    int e = blockIdx.x * 256 + threadIdx.x;
    if (e < N_EDGES) atomicAdd(&cnt[ei[N_EDGES + e]], 1);
}

__global__ __launch_bounds__(256) void dinv_kernel(const int* __restrict__ cnt, float* __restrict__ dinv) {
    int i = blockIdx.x * 256 + threadIdx.x;
    if (i < N_NODES) dinv[i] = rsqrtf((float)(cnt[i] + 1));   // +1 self loop
}

__global__ __launch_bounds__(256) void scan1(const int* __restrict__ cnt, int* __restrict__ partial) {
    __shared__ int sm[256];
    int b = blockIdx.x, t = threadIdx.x;
    int base = b * 512;
    int v = 0;
    if (base + t < N_NODES)       v += cnt[base + t];
    if (base + 256 + t < N_NODES) v += cnt[base + 256 + t];
    sm[t] = v; __syncthreads();
    for (int s = 128; s > 0; s >>= 1) { if (t < s) sm[t] += sm[t + s]; __syncthreads(); }
    if (t == 0) partial[b] = sm[0];
}

__global__ __launch_bounds__(256) void scan2(int* __restrict__ partial, int* __restrict__ row_ptr) {
    __shared__ int sm[256];
    int t = threadIdx.x;
    int v = (t < SCAN_NB) ? partial[t] : 0;
    sm[t] = v; __syncthreads();
    for (int s = 1; s < 256; s <<= 1) {
        int add = (t >= s) ? sm[t - s] : 0;
        __syncthreads();
        sm[t] += add;
        __syncthreads();
    }
    if (t < SCAN_NB) partial[t] = sm[t] - v;          // exclusive
    if (t == 0) row_ptr[N_NODES] = N_EDGES;
}

__global__ __launch_bounds__(256) void scan3(const int* __restrict__ cnt, const int* __restrict__ partial,
                                             int* __restrict__ row_ptr, int* __restrict__ cursor) {
    __shared__ int sm[256];
    int b = blockIdx.x, t = threadIdx.x;
    int base = b * 512;
    int i0 = base + 2 * t, i1 = i0 + 1;
    int e0 = (i0 < N_NODES) ? cnt[i0] : 0;
    int e1 = (i1 < N_NODES) ? cnt[i1] : 0;
    int s2 = e0 + e1;
    sm[t] = s2; __syncthreads();
    for (int s = 1; s < 256; s <<= 1) {
        int add = (t >= s) ? sm[t - s] : 0;
        __syncthreads();
        sm[t] += add;
        __syncthreads();
    }
    int excl = sm[t] - s2 + partial[b];
    if (i0 < N_NODES) { row_ptr[i0] = excl;      cursor[i0] = excl; }
    if (i1 < N_NODES) { row_ptr[i1] = excl + e0; cursor[i1] = excl + e0; }
}

__global__ __launch_bounds__(256) void fill_kernel(const int* __restrict__ ei, int* __restrict__ cursor,
                                                   int* __restrict__ col) {
    int e = blockIdx.x * 256 + threadIdx.x;
    if (e < N_EDGES) {
        int d = ei[N_EDGES + e];
        int p = atomicAdd(&cursor[d], 1);
        col[p] = ei[e];
    }
}

// ---------------- enc1: weight-stationary 32->256 ----------------
// W panel [32 x 128] in LDS once, no K-loop barriers. 2 rows/thread in
// registers (a[2][32] = 64 VGPRs). grid = (ceil(N/512), 2 col panels).
// Inner: 1 ds_read_b128 broadcast + 8 FMA -> VALU-bound (~40-80us total).
__global__ __launch_bounds__(256, 2) void enc1_kernel(
    const float* __restrict__ x, const float* __restrict__ W,
    const float* __restrict__ bias, float* __restrict__ C)
{
    __shared__ float Ws[32][128];
    __shared__ float bs[128];
    int t  = threadIdx.x;
    int c0 = blockIdx.y * 128;
    int r0 = blockIdx.x * 512;

    #pragma unroll
    for (int j = 0; j < 4; ++j) {
        int idx = t + j * 256;            // 0..1023 float4s
        int kk = idx >> 5, cf = idx & 31;
        *(float4*)&Ws[kk][cf * 4] = *(const float4*)&W[kk * 256 + c0 + cf * 4];
    }
    if (t < 32) *(float4*)&bs[t * 4] = *(const float4*)&bias[c0 + t * 4];
    __syncthreads();

    int r1 = r0 + t, r2 = r1 + 256;
    bool v1 = r1 < N_NODES, v2 = r2 < N_NODES;
    float a[2][32];
    #pragma unroll
    for (int j = 0; j < 8; ++j) {
        float4 u = v1 ? *(const float4*)&x[(size_t)r1 * 32 + j * 4] : make_float4(0.f, 0.f, 0.f, 0.f);
        a[0][j * 4] = u.x; a[0][j * 4 + 1] = u.y; a[0][j * 4 + 2] = u.z; a[0][j * 4 + 3] = u.w;
        float4 w = v2 ? *(const float4*)&x[(size_t)r2 * 32 + j * 4] : make_float4(0.f, 0.f, 0.f, 0.f);
        a[1][j * 4] = w.x; a[1][j * 4 + 1] = w.y; a[1][j * 4 + 2] = w.z; a[1][j * 4 + 3] = w.w;
    }

    for (int c4 = 0; c4 < 32; ++c4) {
        float4 b4 = *(const float4*)&bs[c4 * 4];
        float4 s0 = b4, s1 = b4;
        #pragma unroll
        for (int k = 0; k < 32; ++k) {
            float4 w4 = *(const float4*)&Ws[k][c4 * 4];
            s0.x += a[0][k] * w4.x; s0.y += a[0][k] * w4.y;
            s0.z += a[0][k] * w4.z; s0.w += a[0][k] * w4.w;
            s1.x += a[1][k] * w4.x; s1.y += a[1][k] * w4.y;
            s1.z += a[1][k] * w4.z; s1.w += a[1][k] * w4.w;
        }
        s0.x = fmaxf(s0.x, 0.f); s0.y = fmaxf(s0.y, 0.f); s0.z = fmaxf(s0.z, 0.f); s0.w = fmaxf(s0.w, 0.f);
        s1.x = fmaxf(s1.x, 0.f); s1.y = fmaxf(s1.y, 0.f); s1.z = fmaxf(s1.z, 0.f); s1.w = fmaxf(s1.w, 0.f);
        if (v1) *(float4*)&C[(size_t)r1 * 256 + c0 + c4 * 4] = s0;
        if (v2) *(float4*)&C[(size_t)r2 * 256 + c0 + c4 * 4] = s1;
    }
}

// ---------------- shared tiled-GEMM body: C = epilogue(A @ W) ----------------
// 64x64 tile, 256 threads, 4x4 register tile, float4 global staging.
template<int NC, int KTOT, bool HAS_BIAS, bool RELU, bool SCALE, bool GATHER>
__device__ __forceinline__ void gemm_body(
    const float* __restrict__ A, const float* __restrict__ W,
    const float* __restrict__ bias, float* __restrict__ C,
    const float* __restrict__ dinv, const int* __restrict__ gidx, int M)
{
    constexpr int KB = 32;
    __shared__ float As[KB][68];   // transposed [k][row]; pad keeps b128 reads aligned
    __shared__ float Ws[KB][64];

    int t  = threadIdx.x;
    int m0 = blockIdx.x * 64;
    int c0 = blockIdx.y * 64;
    int tx = t & 15, ty = t >> 4;

    float acc[4][4];
    #pragma unroll
    for (int r = 0; r < 4; ++r)
        #pragma unroll
        for (int c = 0; c < 4; ++c) acc[r][c] = 0.f;

    for (int k0 = 0; k0 < KTOT; k0 += KB) {
        // A tile: 64 rows x 32 k = 512 float4, 2 per thread
        #pragma unroll
        for (int j = 0; j < 2; ++j) {
            int idx = t + j * 256;         // 0..511
            int row = idx >> 3;            // 64 rows
            int kf  = idx & 7;             // float4 index within 32-k panel
            int gr  = m0 + row;
            float4 v = make_float4(0.f, 0.f, 0.f, 0.f);
            if (gr < M) {
                if (GATHER) {
                    int gk = k0 + kf * 4;
                    int node = (gk < 64) ? gidx[gr] : gidx[N_EL + gr];
                    v = *(const float4*)&A[(size_t)node * 64 + (gk & 63)];
                } else {
                    v = *(const float4*)&A[(size_t)gr * KTOT + k0 + kf * 4];
                }
            }
            As[kf * 4 + 0][row] = v.x; As[kf * 4 + 1][row] = v.y;
            As[kf * 4 + 2][row] = v.z; As[kf * 4 + 3][row] = v.w;
        }
        // W tile: 32 k x 64 c = 512 float4, 2 per thread
        #pragma unroll
        for (int j = 0; j < 2; ++j) {
            int idx = t + j * 256;
            int kk = idx >> 4, cf = idx & 15;
            *(float4*)&Ws[kk][cf * 4] = *(const float4*)&W[(size_t)(k0 + kk) * NC + c0 + cf * 4];
        }
        __syncthreads();

        #pragma unroll
        for (int kk = 0; kk < KB; ++kk) {
            float4 a4 = *(const float4*)&As[kk][ty * 4];
            float4 w4 = *(const float4*)&Ws[kk][tx * 4];
            acc[0][0] += a4.x * w4.x; acc[0][1] += a4.x * w4.y;
            acc[0][2] += a4.x * w4.z; acc[0][3] += a4.x * w4.w;
            acc[1][0] += a4.y * w4.x; acc[1][1] += a4.y * w4.y;
            acc[1][2] += a4.y * w4.z; acc[1][3] += a4.y * w4.w;
            acc[2][0] += a4.z * w4.x; acc[2][1] += a4.z * w4.y;
            acc[2][2] += a4.z * w4.z; acc[2][3] += a4.z * w4.w;
            acc[3][0] += a4.w * w4.x; acc[3][1] += a4.w * w4.y;
            acc[3][2] += a4.w * w4.z; acc[3][3] += a4.w * w4.w;
        }
        __syncthreads();
    }

    float4 bv = make_float4(0.f, 0.f, 0.f, 0.f);
    if (HAS_BIAS) bv = *(const float4*)&bias[c0 + tx * 4];

    #pragma unroll
    for (int r = 0; r < 4; ++r) {
        int gr = m0 + ty * 4 + r;
        if (gr < M) {
            float4 v;
            v.x = acc[r][0] + bv.x; v.y = acc[r][1] + bv.y;
            v.z = acc[r][2] + bv.z; v.w = acc[r][3] + bv.w;
            if (RELU) {
                v.x = fmaxf(v.x, 0.f); v.y = fmaxf(v.y, 0.f);
                v.z = fmaxf(v.z, 0.f); v.w = fmaxf(v.w, 0.f);
            }
            if (SCALE) {
                float s = dinv[gr];
                v.x *= s; v.y *= s; v.z *= s; v.w *= s;
            }
            *(float4*)&C[(size_t)gr * NC + c0 + tx * 4] = v;
        }
    }
}

// Distinct names per instantiation so rocprof identifies each dispatch.
__global__ __launch_bounds__(256, 4) void gemm_enc2(const float* A, const float* W, const float* b, float* C, int M) {
    gemm_body<128, 256, true, true, false, false>(A, W, b, C, nullptr, nullptr, M);
}
__global__ __launch_bounds__(256, 4) void gemm_conv0(const float* A, const float* W, float* C, const float* dinv, int M) {
    gemm_body<64, 128, false, false, true, false>(A, W, nullptr, C, dinv, nullptr, M);
}
__global__ __launch_bounds__(256, 4) void gemm_conv1(const float* A, const float* W, float* C, const float* dinv, int M) {
    gemm_body<64, 64, false, false, true, false>(A, W, nullptr, C, dinv, nullptr, M);
}
__global__ __launch_bounds__(256, 4) void gemm_conv2(const float* A, const float* W, float* C, const float* dinv, int M) {
    gemm_body<64, 64, false, false, true, false>(A, W, nullptr, C, dinv, nullptr, M);
}
__global__ __launch_bounds__(256, 4) void gemm_ep1(const float* A, const float* W, const float* b, float* C, const int* gidx, int M) {
    gemm_body<128, 128, true, true, false, true>(A, W, b, C, nullptr, gidx, M);
}
__global__ __launch_bounds__(256, 4) void gemm_ep2(const float* A, const float* W, const float* b, float* C, int M) {
    gemm_body<64, 128, true, true, false, false>(A, W, b, C, nullptr, nullptr, M);
}

// ---------------- CSR aggregation: one wave per node, lane = feature ----------------
__global__ __launch_bounds__(256) void agg_kernel(
    const float* __restrict__ y, const int* __restrict__ row_ptr, const int* __restrict__ col,
    const float* __restrict__ dinv, const float* __restrict__ bias,
    float* __restrict__ h, int residual)
{
    int v = blockIdx.x * 4 + (threadIdx.x >> 6);
    int lane = threadIdx.x & 63;
    if (v >= N_NODES) return;
    float acc = y[(size_t)v * 64 + lane];           // self loop
    int s = row_ptr[v], e = row_ptr[v + 1];
    int i = s;
    for (; i + 3 < e; i += 4) {
        int u0 = col[i], u1 = col[i + 1], u2 = col[i + 2], u3 = col[i + 3];
        float f0 = y[(size_t)u0 * 64 + lane];
        float f1 = y[(size_t)u1 * 64 + lane];
        float f2 = y[(size_t)u2 * 64 + lane];
        float f3 = y[(size_t)u3 * 64 + lane];
        acc += f0 + f1 + f2 + f3;
    }
    for (; i < e; ++i) acc += y[(size_t)col[i] * 64 + lane];
    float val = fmaxf(dinv[v] * acc + bias[lane], 0.f);
    size_t o = (size_t)v * 64 + lane;
    if (residual) h[o] += val; else h[o] = val;
}

// ---------------- final edge layer: dot(e2[p], w3) + b3 -> sigmoid ----------------
__global__ __launch_bounds__(256) void ep3_kernel(const float* __restrict__ e2, const float* __restrict__ w3,
                                                  const float* __restrict__ b3, float* __restrict__ out) {
    int p = blockIdx.x * 4 + (threadIdx.x >> 6);
    int lane = threadIdx.x & 63;
    if (p >= N_EL) return;
    float v = e2[(size_t)p * 64 + lane] * w3[lane];
    v += __shfl_xor(v, 32);
    v += __shfl_xor(v, 16);
    v += __shfl_xor(v, 8);
    v += __shfl_xor(v, 4);
    v += __shfl_xor(v, 2);
    v += __shfl_xor(v, 1);
    if (lane == 0) out[p] = 1.f / (1.f + expf(-(v + b3[0])));
}

extern "C" void kernel_launch(void* const* d_in, const int* in_sizes, int n_in,
                              void* d_out, int out_size, void* d_ws, size_t ws_size,
                              hipStream_t stream) {
    const float* x       = (const float*)d_in[0];
    const int*   ei      = (const int*)d_in[1];
    const int*   eli     = (const int*)d_in[2];
    const float* enc_w1  = (const float*)d_in[3];
    const float* enc_b1  = (const float*)d_in[4];
    const float* enc_w2  = (const float*)d_in[5];
    const float* enc_b2  = (const float*)d_in[6];
    const float* conv_w0 = (const float*)d_in[7];
    const float* conv_b0 = (const float*)d_in[8];
    const float* conv_w1 = (const float*)d_in[9];
    const float* conv_b1 = (const float*)d_in[10];
    const float* conv_w2 = (const float*)d_in[11];
    const float* conv_b2 = (const float*)d_in[12];
    const float* ep_w1   = (const float*)d_in[13];
    const float* ep_b1   = (const float*)d_in[14];
    const float* ep_w2   = (const float*)d_in[15];
    const float* ep_b2   = (const float*)d_in[16];
    const float* ep_w3   = (const float*)d_in[17];
    const float* ep_b3   = (const float*)d_in[18];
    float* out = (float*)d_out;

    float* fws     = (float*)d_ws;
    float* h1      = fws;                      // 25,600,000 f  (alias: e1)
    float* h128    = fws + 25600000;           // 12,800,000 f  (alias: e2)
    float* yb      = fws + 38400000;           //  6,400,000 f
    float* h64     = fws + 44800000;           //  6,400,000 f
    int*   col     = (int*)(fws + 51200000);   //  1,600,000 i
    int*   row_ptr = col + 1600000;            //    100,001 i (padded)
    int*   cursor  = row_ptr + 100032;         //    100,000 i
    int*   cnt     = cursor + 100000;          //    100,000 i
    float* dinvp   = (float*)(cnt + 100000);   //    100,000 f
    int*   partial = (int*)(dinvp + 100000);   //        256 i
    float* e1 = h1;
    float* e2 = h128;

    // ---- CSR build ----
    hipMemsetAsync(cnt, 0, N_NODES * sizeof(int), stream);
    deg_kernel <<<(N_EDGES + 255) / 256, 256, 0, stream>>>(ei, cnt);
    dinv_kernel<<<(N_NODES + 255) / 256, 256, 0, stream>>>(cnt, dinvp);
    scan1<<<SCAN_NB, 256, 0, stream>>>(cnt, partial);
    scan2<<<1, 256, 0, stream>>>(partial, row_ptr);
    scan3<<<SCAN_NB, 256, 0, stream>>>(cnt, partial, row_ptr, cursor);
    fill_kernel<<<(N_EDGES + 255) / 256, 256, 0, stream>>>(ei, cursor, col);

    const int GBN = (N_NODES + 63) / 64;   // 1563
    const int GBE = N_EL / 64;             // 3125

    // ---- encoder ----
    enc1_kernel<<<dim3((N_NODES + 511) / 512, 2), 256, 0, stream>>>(x, enc_w1, enc_b1, h1);
    gemm_enc2<<<dim3(GBN, 2), 256, 0, stream>>>(h1, enc_w2, enc_b2, h128, N_NODES);

    // ---- GCN layer 0: 128 -> 64, no residual ----
    gemm_conv0<<<dim3(GBN, 1), 256, 0, stream>>>(h128, conv_w0, yb, dinvp, N_NODES);
    agg_kernel<<<(N_NODES + 3) / 4, 256, 0, stream>>>(yb, row_ptr, col, dinvp, conv_b0, h64, 0);

    // ---- GCN layer 1: 64 -> 64, residual (in-place safe: wave owns its row) ----
    gemm_conv1<<<dim3(GBN, 1), 256, 0, stream>>>(h64, conv_w1, yb, dinvp, N_NODES);
    agg_kernel<<<(N_NODES + 3) / 4, 256, 0, stream>>>(yb, row_ptr, col, dinvp, conv_b1, h64, 1);

    // ---- GCN layer 2 ----
    gemm_conv2<<<dim3(GBN, 1), 256, 0, stream>>>(h64, conv_w2, yb, dinvp, N_NODES);
    agg_kernel<<<(N_NODES + 3) / 4, 256, 0, stream>>>(yb, row_ptr, col, dinvp, conv_b2, h64, 1);

    // ---- edge predictor ----
    gemm_ep1<<<dim3(GBE, 2), 256, 0, stream>>>(h64, ep_w1, ep_b1, e1, eli, N_EL);
    gemm_ep2<<<dim3(GBE, 1), 256, 0, stream>>>(e1, ep_w2, ep_b2, e2, N_EL);
    ep3_kernel<<<(N_EL + 3) / 4, 256, 0, stream>>>(e2, ep_w3, ep_b3, out);
}

// Round 4
// 807.297 us; speedup vs baseline: 13.5079x; 1.1089x over previous
//
#include <hip/hip_runtime.h>
#include <math.h>

// ---------------------------------------------------------------------------
// EmergencyGNNEnhanced: encoder (32->256->128) -> 3x GCN (->64) -> edge MLP.
// All fp32. CSR built on-device each call (graph-capture safe, same work).
// Aggregation: agg[v] = dinv[v]*(sum_{u->v} y[u] + y[v]),  y = dinv .* (h@W).
//
// R3 postmortem: fill_kernel is the steady-state #1 (125us, WRITE_SIZE=105MB
// = 64B/edge: every random 4B col write evicts a near-empty line). enc1's
// writes were 2.5x amplified (lane=row => 16B stores 1KB apart).
// R4: (a) fill windowed by dst with blockIdx%8 XCD-swizzle so each 800KB col
// window is written by one XCD's L2 -> full-line writebacks; (b) enc1
// rewritten lane=column with LDS W panel + transposed x tile -> coalesced
// 1KB/wave stores, broadcast LDS reads.
// ---------------------------------------------------------------------------

#define N_NODES 100000
#define N_EDGES 1600000
#define N_EL    200000
#define SCAN_NB 196          // ceil(100000/512)
#define FILL_WIN 12500       // N_NODES/8 dst window per XCD group

// ---------------- CSR build ----------------
__global__ __launch_bounds__(256) void deg_kernel(const int* __restrict__ ei, int* __restrict__ cnt) {
    int e = blockIdx.x * 256 + threadIdx.x;
    if (e < N_EDGES) atomicAdd(&cnt[ei[N_EDGES + e]], 1);
}

__global__ __launch_bounds__(256) void dinv_kernel(const int* __restrict__ cnt, float* __restrict__ dinv) {
    int i = blockIdx.x * 256 + threadIdx.x;
    if (i < N_NODES) dinv[i] = rsqrtf((float)(cnt[i] + 1));   // +1 self loop
}

__global__ __launch_bounds__(256) void scan1(const int* __restrict__ cnt, int* __restrict__ partial) {
    __shared__ int sm[256];
    int b = blockIdx.x, t = threadIdx.x;
    int base = b * 512;
    int v = 0;
    if (base + t < N_NODES)       v += cnt[base + t];
    if (base + 256 + t < N_NODES) v += cnt[base + 256 + t];
    sm[t] = v; __syncthreads();
    for (int s = 128; s > 0; s >>= 1) { if (t < s) sm[t] += sm[t + s]; __syncthreads(); }
    if (t == 0) partial[b] = sm[0];
}

__global__ __launch_bounds__(256) void scan2(int* __restrict__ partial, int* __restrict__ row_ptr) {
    __shared__ int sm[256];
    int t = threadIdx.x;
    int v = (t < SCAN_NB) ? partial[t] : 0;
    sm[t] = v; __syncthreads();
    for (int s = 1; s < 256; s <<= 1) {
        int add = (t >= s) ? sm[t - s] : 0;
        __syncthreads();
        sm[t] += add;
        __syncthreads();
    }
    if (t < SCAN_NB) partial[t] = sm[t] - v;          // exclusive
    if (t == 0) row_ptr[N_NODES] = N_EDGES;
}

__global__ __launch_bounds__(256) void scan3(const int* __restrict__ cnt, const int* __restrict__ partial,
                                             int* __restrict__ row_ptr, int* __restrict__ cursor) {
    __shared__ int sm[256];
    int b = blockIdx.x, t = threadIdx.x;
    int base = b * 512;
    int i0 = base + 2 * t, i1 = i0 + 1;
    int e0 = (i0 < N_NODES) ? cnt[i0] : 0;
    int e1 = (i1 < N_NODES) ? cnt[i1] : 0;
    int s2 = e0 + e1;
    sm[t] = s2; __syncthreads();
    for (int s = 1; s < 256; s <<= 1) {
        int add = (t >= s) ? sm[t - s] : 0;
        __syncthreads();
        sm[t] += add;
        __syncthreads();
    }
    int excl = sm[t] - s2 + partial[b];
    if (i0 < N_NODES) { row_ptr[i0] = excl;      cursor[i0] = excl; }
    if (i1 < N_NODES) { row_ptr[i1] = excl + e0; cursor[i1] = excl + e0; }
}

// Windowed fill: group w = blockIdx%8 handles dst in [w*12500,(w+1)*12500).
// With the blockIdx%8 -> XCD round-robin heuristic, each col window (~800KB)
// is written by one XCD's L2, so 64B lines (= one node's avg 16-entry
// segment) fill completely before writeback. dst re-reads are L3-absorbed.
// Correct under ANY block->XCD mapping (only traffic changes).
__global__ __launch_bounds__(256) void fill_kernel(const int* __restrict__ ei, int* __restrict__ cursor,
                                                   int* __restrict__ col) {
    int w  = blockIdx.x & 7;
    int lo = w * FILL_WIN, hi = lo + FILL_WIN;   // last window: hi=100000 exactly
    int nb = gridDim.x >> 3;
    int bi = blockIdx.x >> 3;
    for (int e = bi * 256 + (int)threadIdx.x; e < N_EDGES; e += nb * 256) {
        int d = ei[N_EDGES + e];
        if (d >= lo && d < hi) {
            int p = atomicAdd(&cursor[d], 1);
            col[p] = ei[e];
        }
    }
}

// ---------------- enc1: weight-stationary 32->256, coalesced writes ----------
// Block = 64 rows x 256 cols. LDS: W[32][256] (32KB) + x^T[32][68] (8.7KB).
// Thread (tx=t&63, ty=t>>6): 16 rows x 4 cols, acc in 16 float4. Lane = col
// quad -> stores are 1KB contiguous per wave-row. A reads are wave-uniform
// ds_read_b128 broadcasts (ty uniform within a wave).
__global__ __launch_bounds__(256, 2) void enc1_kernel(
    const float* __restrict__ x, const float* __restrict__ W,
    const float* __restrict__ bias, float* __restrict__ C)
{
    __shared__ float Ws[32][256];
    __shared__ float xt[32][68];    // [k][row], stride 68 keeps b128 16B-aligned
    __shared__ float bs[256];

    int t  = threadIdx.x;
    int r0 = blockIdx.x * 64;

    #pragma unroll
    for (int j = 0; j < 8; ++j) {
        int idx = t + j * 256;              // 0..2047 float4s
        int kk = idx >> 6, cf = idx & 63;
        *(float4*)&Ws[kk][cf * 4] = *(const float4*)&W[kk * 256 + cf * 4];
    }
    if (t < 64) *(float4*)&bs[t * 4] = *(const float4*)&bias[t * 4];

    #pragma unroll
    for (int j = 0; j < 2; ++j) {
        int fidx = t + j * 256;             // 0..511
        int row = fidx >> 3, kf = fidx & 7;
        int gr = r0 + row;
        float4 v = (gr < N_NODES) ? *(const float4*)&x[(size_t)gr * 32 + kf * 4]
                                  : make_float4(0.f, 0.f, 0.f, 0.f);
        xt[kf * 4 + 0][row] = v.x; xt[kf * 4 + 1][row] = v.y;
        xt[kf * 4 + 2][row] = v.z; xt[kf * 4 + 3][row] = v.w;
    }
    __syncthreads();

    int tx = t & 63, ty = t >> 6;
    float4 b4 = *(const float4*)&bs[tx * 4];
    float4 acc[16];
    #pragma unroll
    for (int r = 0; r < 16; ++r) acc[r] = b4;

    #pragma unroll 4
    for (int k = 0; k < 32; ++k) {
        float4 w4 = *(const float4*)&Ws[k][tx * 4];
        #pragma unroll
        for (int j = 0; j < 4; ++j) {
            float4 a4 = *(const float4*)&xt[k][ty * 16 + j * 4];   // broadcast
            acc[j * 4 + 0].x += a4.x * w4.x; acc[j * 4 + 0].y += a4.x * w4.y;
            acc[j * 4 + 0].z += a4.x * w4.z; acc[j * 4 + 0].w += a4.x * w4.w;
            acc[j * 4 + 1].x += a4.y * w4.x; acc[j * 4 + 1].y += a4.y * w4.y;
            acc[j * 4 + 1].z += a4.y * w4.z; acc[j * 4 + 1].w += a4.y * w4.w;
            acc[j * 4 + 2].x += a4.z * w4.x; acc[j * 4 + 2].y += a4.z * w4.y;
            acc[j * 4 + 2].z += a4.z * w4.z; acc[j * 4 + 2].w += a4.z * w4.w;
            acc[j * 4 + 3].x += a4.w * w4.x; acc[j * 4 + 3].y += a4.w * w4.y;
            acc[j * 4 + 3].z += a4.w * w4.z; acc[j * 4 + 3].w += a4.w * w4.w;
        }
    }

    #pragma unroll
    for (int r = 0; r < 16; ++r) {
        int gr = r0 + ty * 16 + r;
        if (gr < N_NODES) {
            float4 v = acc[r];
            v.x = fmaxf(v.x, 0.f); v.y = fmaxf(v.y, 0.f);
            v.z = fmaxf(v.z, 0.f); v.w = fmaxf(v.w, 0.f);
            *(float4*)&C[(size_t)gr * 256 + tx * 4] = v;
        }
    }
}

// ---------------- shared tiled-GEMM body: C = epilogue(A @ W) ----------------
// 64x64 tile, 256 threads, 4x4 register tile, float4 global staging.
template<int NC, int KTOT, bool HAS_BIAS, bool RELU, bool SCALE, bool GATHER>
__device__ __forceinline__ void gemm_body(
    const float* __restrict__ A, const float* __restrict__ W,
    const float* __restrict__ bias, float* __restrict__ C,
    const float* __restrict__ dinv, const int* __restrict__ gidx, int M)
{
    constexpr int KB = 32;
    __shared__ float As[KB][68];   // transposed [k][row]; pad keeps b128 reads aligned
    __shared__ float Ws[KB][64];

    int t  = threadIdx.x;
    int m0 = blockIdx.x * 64;
    int c0 = blockIdx.y * 64;
    int tx = t & 15, ty = t >> 4;

    float acc[4][4];
    #pragma unroll
    for (int r = 0; r < 4; ++r)
        #pragma unroll
        for (int c = 0; c < 4; ++c) acc[r][c] = 0.f;

    for (int k0 = 0; k0 < KTOT; k0 += KB) {
        // A tile: 64 rows x 32 k = 512 float4, 2 per thread
        #pragma unroll
        for (int j = 0; j < 2; ++j) {
            int idx = t + j * 256;         // 0..511
            int row = idx >> 3;            // 64 rows
            int kf  = idx & 7;             // float4 index within 32-k panel
            int gr  = m0 + row;
            float4 v = make_float4(0.f, 0.f, 0.f, 0.f);
            if (gr < M) {
                if (GATHER) {
                    int gk = k0 + kf * 4;
                    int node = (gk < 64) ? gidx[gr] : gidx[N_EL + gr];
                    v = *(const float4*)&A[(size_t)node * 64 + (gk & 63)];
                } else {
                    v = *(const float4*)&A[(size_t)gr * KTOT + k0 + kf * 4];
                }
            }
            As[kf * 4 + 0][row] = v.x; As[kf * 4 + 1][row] = v.y;
            As[kf * 4 + 2][row] = v.z; As[kf * 4 + 3][row] = v.w;
        }
        // W tile: 32 k x 64 c = 512 float4, 2 per thread
        #pragma unroll
        for (int j = 0; j < 2; ++j) {
            int idx = t + j * 256;
            int kk = idx >> 4, cf = idx & 15;
            *(float4*)&Ws[kk][cf * 4] = *(const float4*)&W[(size_t)(k0 + kk) * NC + c0 + cf * 4];
        }
        __syncthreads();

        #pragma unroll
        for (int kk = 0; kk < KB; ++kk) {
            float4 a4 = *(const float4*)&As[kk][ty * 4];
            float4 w4 = *(const float4*)&Ws[kk][tx * 4];
            acc[0][0] += a4.x * w4.x; acc[0][1] += a4.x * w4.y;
            acc[0][2] += a4.x * w4.z; acc[0][3] += a4.x * w4.w;
            acc[1][0] += a4.y * w4.x; acc[1][1] += a4.y * w4.y;
            acc[1][2] += a4.y * w4.z; acc[1][3] += a4.y * w4.w;
            acc[2][0] += a4.z * w4.x; acc[2][1] += a4.z * w4.y;
            acc[2][2] += a4.z * w4.z; acc[2][3] += a4.z * w4.w;
            acc[3][0] += a4.w * w4.x; acc[3][1] += a4.w * w4.y;
            acc[3][2] += a4.w * w4.z; acc[3][3] += a4.w * w4.w;
        }
        __syncthreads();
    }

    float4 bv = make_float4(0.f, 0.f, 0.f, 0.f);
    if (HAS_BIAS) bv = *(const float4*)&bias[c0 + tx * 4];

    #pragma unroll
    for (int r = 0; r < 4; ++r) {
        int gr = m0 + ty * 4 + r;
        if (gr < M) {
            float4 v;
            v.x = acc[r][0] + bv.x; v.y = acc[r][1] + bv.y;
            v.z = acc[r][2] + bv.z; v.w = acc[r][3] + bv.w;
            if (RELU) {
                v.x = fmaxf(v.x, 0.f); v.y = fmaxf(v.y, 0.f);
                v.z = fmaxf(v.z, 0.f); v.w = fmaxf(v.w, 0.f);
            }
            if (SCALE) {
                float s = dinv[gr];
                v.x *= s; v.y *= s; v.z *= s; v.w *= s;
            }
            *(float4*)&C[(size_t)gr * NC + c0 + tx * 4] = v;
        }
    }
}

// Distinct names per instantiation so rocprof identifies each dispatch.
__global__ __launch_bounds__(256, 4) void gemm_enc2(const float* A, const float* W, const float* b, float* C, int M) {
    gemm_body<128, 256, true, true, false, false>(A, W, b, C, nullptr, nullptr, M);
}
__global__ __launch_bounds__(256, 4) void gemm_conv0(const float* A, const float* W, float* C, const float* dinv, int M) {
    gemm_body<64, 128, false, false, true, false>(A, W, nullptr, C, dinv, nullptr, M);
}
__global__ __launch_bounds__(256, 4) void gemm_conv1(const float* A, const float* W, float* C, const float* dinv, int M) {
    gemm_body<64, 64, false, false, true, false>(A, W, nullptr, C, dinv, nullptr, M);
}
__global__ __launch_bounds__(256, 4) void gemm_conv2(const float* A, const float* W, float* C, const float* dinv, int M) {
    gemm_body<64, 64, false, false, true, false>(A, W, nullptr, C, dinv, nullptr, M);
}
__global__ __launch_bounds__(256, 4) void gemm_ep1(const float* A, const float* W, const float* b, float* C, const int* gidx, int M) {
    gemm_body<128, 128, true, true, false, true>(A, W, b, C, nullptr, gidx, M);
}
__global__ __launch_bounds__(256, 4) void gemm_ep2(const float* A, const float* W, const float* b, float* C, int M) {
    gemm_body<64, 128, true, true, false, false>(A, W, b, C, nullptr, nullptr, M);
}

// ---------------- CSR aggregation: one wave per node, lane = feature ----------------
__global__ __launch_bounds__(256) void agg_kernel(
    const float* __restrict__ y, const int* __restrict__ row_ptr, const int* __restrict__ col,
    const float* __restrict__ dinv, const float* __restrict__ bias,
    float* __restrict__ h, int residual)
{
    int v = blockIdx.x * 4 + (threadIdx.x >> 6);
    int lane = threadIdx.x & 63;
    if (v >= N_NODES) return;
    float acc = y[(size_t)v * 64 + lane];           // self loop
    int s = row_ptr[v], e = row_ptr[v + 1];
    int i = s;
    for (; i + 3 < e; i += 4) {
        int u0 = col[i], u1 = col[i + 1], u2 = col[i + 2], u3 = col[i + 3];
        float f0 = y[(size_t)u0 * 64 + lane];
        float f1 = y[(size_t)u1 * 64 + lane];
        float f2 = y[(size_t)u2 * 64 + lane];
        float f3 = y[(size_t)u3 * 64 + lane];
        acc += f0 + f1 + f2 + f3;
    }
    for (; i < e; ++i) acc += y[(size_t)col[i] * 64 + lane];
    float val = fmaxf(dinv[v] * acc + bias[lane], 0.f);
    size_t o = (size_t)v * 64 + lane;
    if (residual) h[o] += val; else h[o] = val;
}

// ---------------- final edge layer: dot(e2[p], w3) + b3 -> sigmoid ----------------
__global__ __launch_bounds__(256) void ep3_kernel(const float* __restrict__ e2, const float* __restrict__ w3,
                                                  const float* __restrict__ b3, float* __restrict__ out) {
    int p = blockIdx.x * 4 + (threadIdx.x >> 6);
    int lane = threadIdx.x & 63;
    if (p >= N_EL) return;
    float v = e2[(size_t)p * 64 + lane] * w3[lane];
    v += __shfl_xor(v, 32);
    v += __shfl_xor(v, 16);
    v += __shfl_xor(v, 8);
    v += __shfl_xor(v, 4);
    v += __shfl_xor(v, 2);
    v += __shfl_xor(v, 1);
    if (lane == 0) out[p] = 1.f / (1.f + expf(-(v + b3[0])));
}

extern "C" void kernel_launch(void* const* d_in, const int* in_sizes, int n_in,
                              void* d_out, int out_size, void* d_ws, size_t ws_size,
                              hipStream_t stream) {
    const float* x       = (const float*)d_in[0];
    const int*   ei      = (const int*)d_in[1];
    const int*   eli     = (const int*)d_in[2];
    const float* enc_w1  = (const float*)d_in[3];
    const float* enc_b1  = (const float*)d_in[4];
    const float* enc_w2  = (const float*)d_in[5];
    const float* enc_b2  = (const float*)d_in[6];
    const float* conv_w0 = (const float*)d_in[7];
    const float* conv_b0 = (const float*)d_in[8];
    const float* conv_w1 = (const float*)d_in[9];
    const float* conv_b1 = (const float*)d_in[10];
    const float* conv_w2 = (const float*)d_in[11];
    const float* conv_b2 = (const float*)d_in[12];
    const float* ep_w1   = (const float*)d_in[13];
    const float* ep_b1   = (const float*)d_in[14];
    const float* ep_w2   = (const float*)d_in[15];
    const float* ep_b2   = (const float*)d_in[16];
    const float* ep_w3   = (const float*)d_in[17];
    const float* ep_b3   = (const float*)d_in[18];
    float* out = (float*)d_out;

    float* fws     = (float*)d_ws;
    float* h1      = fws;                      // 25,600,000 f  (alias: e1)
    float* h128    = fws + 25600000;           // 12,800,000 f  (alias: e2)
    float* yb      = fws + 38400000;           //  6,400,000 f
    float* h64     = fws + 44800000;           //  6,400,000 f
    int*   col     = (int*)(fws + 51200000);   //  1,600,000 i
    int*   row_ptr = col + 1600000;            //    100,001 i (padded)
    int*   cursor  = row_ptr + 100032;         //    100,000 i
    int*   cnt     = cursor + 100000;          //    100,000 i
    float* dinvp   = (float*)(cnt + 100000);   //    100,000 f
    int*   partial = (int*)(dinvp + 100000);   //        256 i
    float* e1 = h1;
    float* e2 = h128;

    // ---- CSR build ----
    hipMemsetAsync(cnt, 0, N_NODES * sizeof(int), stream);
    deg_kernel <<<(N_EDGES + 255) / 256, 256, 0, stream>>>(ei, cnt);
    dinv_kernel<<<(N_NODES + 255) / 256, 256, 0, stream>>>(cnt, dinvp);
    scan1<<<SCAN_NB, 256, 0, stream>>>(cnt, partial);
    scan2<<<1, 256, 0, stream>>>(partial, row_ptr);
    scan3<<<SCAN_NB, 256, 0, stream>>>(cnt, partial, row_ptr, cursor);
    fill_kernel<<<2048, 256, 0, stream>>>(ei, cursor, col);

    const int GBN = (N_NODES + 63) / 64;   // 1563
    const int GBE = N_EL / 64;             // 3125

    // ---- encoder ----
    enc1_kernel<<<dim3(GBN), 256, 0, stream>>>(x, enc_w1, enc_b1, h1);
    gemm_enc2<<<dim3(GBN, 2), 256, 0, stream>>>(h1, enc_w2, enc_b2, h128, N_NODES);

    // ---- GCN layer 0: 128 -> 64, no residual ----
    gemm_conv0<<<dim3(GBN, 1), 256, 0, stream>>>(h128, conv_w0, yb, dinvp, N_NODES);
    agg_kernel<<<(N_NODES + 3) / 4, 256, 0, stream>>>(yb, row_ptr, col, dinvp, conv_b0, h64, 0);

    // ---- GCN layer 1: 64 -> 64, residual (in-place safe: wave owns its row) ----
    gemm_conv1<<<dim3(GBN, 1), 256, 0, stream>>>(h64, conv_w1, yb, dinvp, N_NODES);
    agg_kernel<<<(N_NODES + 3) / 4, 256, 0, stream>>>(yb, row_ptr, col, dinvp, conv_b1, h64, 1);

    // ---- GCN layer 2 ----
    gemm_conv2<<<dim3(GBN, 1), 256, 0, stream>>>(h64, conv_w2, yb, dinvp, N_NODES);
    agg_kernel<<<(N_NODES + 3) / 4, 256, 0, stream>>>(yb, row_ptr, col, dinvp, conv_b2, h64, 1);

    // ---- edge predictor ----
    gemm_ep1<<<dim3(GBE, 2), 256, 0, stream>>>(h64, ep_w1, ep_b1, e1, eli, N_EL);
    gemm_ep2<<<dim3(GBE, 1), 256, 0, stream>>>(e1, ep_w2, ep_b2, e2, N_EL);
    ep3_kernel<<<(N_EL + 3) / 4, 256, 0, stream>>>(e2, ep_w3, ep_b3, out);
}

// Round 5
// 667.981 us; speedup vs baseline: 16.3251x; 1.2086x over previous
//
#include <hip/hip_runtime.h>
#include <math.h>

// ---------------------------------------------------------------------------
// EmergencyGNNEnhanced: encoder (32->256->128) -> 3x GCN (->64) -> edge MLP.
// CSR built on-device each call. agg[v] = dinv[v]*(sum_{u->v} y[u] + y[v]).
//
// R5: enc2/ep1/ep2 converted to bf16 MFMA (16x16x32). fp32 vector path kept
// for conv gemms + aggregation (exact). h1 stored bf16 by enc1; agg layer 2
// emits bf16 h64 for ep1's gather. Weights pre-swizzled on device into
// B-fragment order. Layouts (HW-verified m89/m91/m120):
//   A[m=lane&15][k=(lane>>4)*8+j], B[k=(lane>>4)*8+j][n=lane&15],
//   D col=lane&15, row=(lane>>4)*4+reg.
// ---------------------------------------------------------------------------

#define N_NODES 100000
#define N_EDGES 1600000
#define N_EL    200000
#define SCAN_NB 196          // ceil(100000/512)
#define FILL_WIN 12500       // N_NODES/8 dst window per XCD group

typedef __attribute__((ext_vector_type(8))) short short8_t;
typedef __attribute__((ext_vector_type(4))) float f32x4;

__device__ __forceinline__ unsigned short f2bf(float f) {
    unsigned u = __float_as_uint(f);
    unsigned r = u + 0x7FFFu + ((u >> 16) & 1u);   // RNE
    return (unsigned short)(r >> 16);
}

// ---------------- CSR build ----------------
__global__ __launch_bounds__(256) void deg_kernel(const int* __restrict__ ei, int* __restrict__ cnt) {
    int e = blockIdx.x * 256 + threadIdx.x;
    if (e < N_EDGES) atomicAdd(&cnt[ei[N_EDGES + e]], 1);
}

__global__ __launch_bounds__(256) void dinv_kernel(const int* __restrict__ cnt, float* __restrict__ dinv) {
    int i = blockIdx.x * 256 + threadIdx.x;
    if (i < N_NODES) dinv[i] = rsqrtf((float)(cnt[i] + 1));   // +1 self loop
}

__global__ __launch_bounds__(256) void scan1(const int* __restrict__ cnt, int* __restrict__ partial) {
    __shared__ int sm[256];
    int b = blockIdx.x, t = threadIdx.x;
    int base = b * 512;
    int v = 0;
    if (base + t < N_NODES)       v += cnt[base + t];
    if (base + 256 + t < N_NODES) v += cnt[base + 256 + t];
    sm[t] = v; __syncthreads();
    for (int s = 128; s > 0; s >>= 1) { if (t < s) sm[t] += sm[t + s]; __syncthreads(); }
    if (t == 0) partial[b] = sm[0];
}

__global__ __launch_bounds__(256) void scan2(int* __restrict__ partial, int* __restrict__ row_ptr) {
    __shared__ int sm[256];
    int t = threadIdx.x;
    int v = (t < SCAN_NB) ? partial[t] : 0;
    sm[t] = v; __syncthreads();
    for (int s = 1; s < 256; s <<= 1) {
        int add = (t >= s) ? sm[t - s] : 0;
        __syncthreads();
        sm[t] += add;
        __syncthreads();
    }
    if (t < SCAN_NB) partial[t] = sm[t] - v;          // exclusive
    if (t == 0) row_ptr[N_NODES] = N_EDGES;
}

__global__ __launch_bounds__(256) void scan3(const int* __restrict__ cnt, const int* __restrict__ partial,
                                             int* __restrict__ row_ptr, int* __restrict__ cursor) {
    __shared__ int sm[256];
    int b = blockIdx.x, t = threadIdx.x;
    int base = b * 512;
    int i0 = base + 2 * t, i1 = i0 + 1;
    int e0 = (i0 < N_NODES) ? cnt[i0] : 0;
    int e1 = (i1 < N_NODES) ? cnt[i1] : 0;
    int s2 = e0 + e1;
    sm[t] = s2; __syncthreads();
    for (int s = 1; s < 256; s <<= 1) {
        int add = (t >= s) ? sm[t - s] : 0;
        __syncthreads();
        sm[t] += add;
        __syncthreads();
    }
    int excl = sm[t] - s2 + partial[b];
    if (i0 < N_NODES) { row_ptr[i0] = excl;      cursor[i0] = excl; }
    if (i1 < N_NODES) { row_ptr[i1] = excl + e0; cursor[i1] = excl + e0; }
}

// Windowed fill (R4): dst-window per blockIdx%8 XCD group -> full-line writes.
__global__ __launch_bounds__(256) void fill_kernel(const int* __restrict__ ei, int* __restrict__ cursor,
                                                   int* __restrict__ col) {
    int w  = blockIdx.x & 7;
    int lo = w * FILL_WIN, hi = lo + FILL_WIN;
    int nb = gridDim.x >> 3;
    int bi = blockIdx.x >> 3;
    for (int e = bi * 256 + (int)threadIdx.x; e < N_EDGES; e += nb * 256) {
        int d = ei[N_EDGES + e];
        if (d >= lo && d < hi) {
            int p = atomicAdd(&cursor[d], 1);
            col[p] = ei[e];
        }
    }
}

// ---------------- enc1: weight-stationary 32->256, bf16 output ----------------
__global__ __launch_bounds__(256, 2) void enc1_kernel(
    const float* __restrict__ x, const float* __restrict__ W,
    const float* __restrict__ bias, unsigned short* __restrict__ C)
{
    __shared__ float Ws[32][256];
    __shared__ float xt[32][68];
    __shared__ float bs[256];

    int t  = threadIdx.x;
    int r0 = blockIdx.x * 64;

    #pragma unroll
    for (int j = 0; j < 8; ++j) {
        int idx = t + j * 256;
        int kk = idx >> 6, cf = idx & 63;
        *(float4*)&Ws[kk][cf * 4] = *(const float4*)&W[kk * 256 + cf * 4];
    }
    if (t < 64) *(float4*)&bs[t * 4] = *(const float4*)&bias[t * 4];

    #pragma unroll
    for (int j = 0; j < 2; ++j) {
        int fidx = t + j * 256;
        int row = fidx >> 3, kf = fidx & 7;
        int gr = r0 + row;
        float4 v = (gr < N_NODES) ? *(const float4*)&x[(size_t)gr * 32 + kf * 4]
                                  : make_float4(0.f, 0.f, 0.f, 0.f);
        xt[kf * 4 + 0][row] = v.x; xt[kf * 4 + 1][row] = v.y;
        xt[kf * 4 + 2][row] = v.z; xt[kf * 4 + 3][row] = v.w;
    }
    __syncthreads();

    int tx = t & 63, ty = t >> 6;
    float4 b4 = *(const float4*)&bs[tx * 4];
    float4 acc[16];
    #pragma unroll
    for (int r = 0; r < 16; ++r) acc[r] = b4;

    #pragma unroll 4
    for (int k = 0; k < 32; ++k) {
        float4 w4 = *(const float4*)&Ws[k][tx * 4];
        #pragma unroll
        for (int j = 0; j < 4; ++j) {
            float4 a4 = *(const float4*)&xt[k][ty * 16 + j * 4];
            acc[j * 4 + 0].x += a4.x * w4.x; acc[j * 4 + 0].y += a4.x * w4.y;
            acc[j * 4 + 0].z += a4.x * w4.z; acc[j * 4 + 0].w += a4.x * w4.w;
            acc[j * 4 + 1].x += a4.y * w4.x; acc[j * 4 + 1].y += a4.y * w4.y;
            acc[j * 4 + 1].z += a4.y * w4.z; acc[j * 4 + 1].w += a4.y * w4.w;
            acc[j * 4 + 2].x += a4.z * w4.x; acc[j * 4 + 2].y += a4.z * w4.y;
            acc[j * 4 + 2].z += a4.z * w4.z; acc[j * 4 + 2].w += a4.z * w4.w;
            acc[j * 4 + 3].x += a4.w * w4.x; acc[j * 4 + 3].y += a4.w * w4.y;
            acc[j * 4 + 3].z += a4.w * w4.z; acc[j * 4 + 3].w += a4.w * w4.w;
        }
    }

    #pragma unroll
    for (int r = 0; r < 16; ++r) {
        int gr = r0 + ty * 16 + r;
        if (gr < N_NODES) {
            float4 v = acc[r];
            unsigned p0 = (unsigned)f2bf(fmaxf(v.x, 0.f)) | ((unsigned)f2bf(fmaxf(v.y, 0.f)) << 16);
            unsigned p1 = (unsigned)f2bf(fmaxf(v.z, 0.f)) | ((unsigned)f2bf(fmaxf(v.w, 0.f)) << 16);
            *(uint2*)&C[(size_t)gr * 256 + tx * 4] = make_uint2(p0, p1);
        }
    }
}

// ---------------- weight swizzle: fp32 W[K][N] -> bf16 B-fragment order -----
// Wp flat = (((chunk*(N/16)+ntile)*2+kstep)*64+lane)*8+j
//   <- W[k=chunk*64+kstep*32+(lane>>4)*8+j][n=ntile*16+(lane&15)]
template<int KTOT, int NTOT>
__global__ __launch_bounds__(256) void wprep_kernel(const float* __restrict__ W, unsigned short* __restrict__ Wp) {
    int flat = blockIdx.x * 256 + threadIdx.x;
    if (flat >= KTOT * NTOT) return;
    int j = flat & 7, lane = (flat >> 3) & 63, kstep = (flat >> 9) & 1;
    int rest = flat >> 10;
    int ntile = rest % (NTOT / 16), chunk = rest / (NTOT / 16);
    int k = chunk * 64 + kstep * 32 + (lane >> 4) * 8 + j;
    int n = ntile * 16 + (lane & 15);
    Wp[flat] = f2bf(W[(size_t)k * NTOT + n]);
}

// ---------------- bf16 MFMA GEMM: C = relu(A@W + b) ----------------
// 64 rows/block, 4 waves: wave = 16 rows x NTOT cols. K in 64-chunks.
template<int NTOT, int KTOT, bool GATHER, bool OUT_BF16>
__device__ __forceinline__ void mfma_gemm_body(
    const unsigned short* __restrict__ A, const unsigned short* __restrict__ Wp,
    const float* __restrict__ bias, void* __restrict__ Cout,
    const int* __restrict__ gidx, int M)
{
    constexpr int NT16 = NTOT / 16;
    constexpr int NCH  = KTOT / 64;
    __shared__ unsigned short As[64][72];           // 72-pad: 2-way banks on frag reads
    __shared__ unsigned short Wls[NT16 * 1024];

    int t = threadIdx.x, wave = t >> 6, lane = t & 63;
    int m0 = blockIdx.x * 64;

    f32x4 acc[NT16];
    #pragma unroll
    for (int nt = 0; nt < NT16; ++nt) acc[nt] = (f32x4){0.f, 0.f, 0.f, 0.f};

    for (int ch = 0; ch < NCH; ++ch) {
        // stage A: 64 rows x 64 k bf16 (16B per thread-chunk)
        #pragma unroll
        for (int j = 0; j < 2; ++j) {
            int idx = t + j * 256;
            int row = idx >> 3, seg = idx & 7;
            int gr = m0 + row;
            uint4 v = make_uint4(0u, 0u, 0u, 0u);
            if (gr < M) {
                const unsigned short* src;
                if (GATHER) {
                    int node = (ch == 0) ? gidx[gr] : gidx[N_EL + gr];
                    src = A + (size_t)node * 64 + seg * 8;
                } else {
                    src = A + (size_t)gr * KTOT + ch * 64 + seg * 8;
                }
                v = *(const uint4*)src;
            }
            *(uint4*)&As[row][seg * 8] = v;
        }
        // stage swizzled W chunk (contiguous copy)
        constexpr int WL16 = NT16 * 128;            // uint4 count
        #pragma unroll
        for (int j = 0; j < WL16 / 256; ++j) {
            int idx = t + j * 256;
            ((uint4*)Wls)[idx] = ((const uint4*)(Wp + (size_t)ch * NT16 * 1024))[idx];
        }
        __syncthreads();

        #pragma unroll
        for (int ks = 0; ks < 2; ++ks) {
            short8_t af = *(const short8_t*)&As[wave * 16 + (lane & 15)][ks * 32 + (lane >> 4) * 8];
            #pragma unroll
            for (int nt = 0; nt < NT16; ++nt) {
                short8_t bf = *(const short8_t*)&Wls[((nt * 2 + ks) * 64 + lane) * 8];
                acc[nt] = __builtin_amdgcn_mfma_f32_16x16x32_bf16(af, bf, acc[nt], 0, 0, 0);
            }
        }
        __syncthreads();
    }

    int cb = lane & 15, rq = lane >> 4;
    #pragma unroll
    for (int nt = 0; nt < NT16; ++nt) {
        int col = nt * 16 + cb;
        float bv = bias[col];
        #pragma unroll
        for (int r = 0; r < 4; ++r) {
            int gr = m0 + wave * 16 + rq * 4 + r;
            if (gr < M) {
                float val = fmaxf(acc[nt][r] + bv, 0.f);
                if (OUT_BF16) ((unsigned short*)Cout)[(size_t)gr * NTOT + col] = f2bf(val);
                else          ((float*)Cout)[(size_t)gr * NTOT + col] = val;
            }
        }
    }
}

__global__ __launch_bounds__(256, 4) void mfma_enc2(const unsigned short* A, const unsigned short* Wp,
                                                    const float* b, float* C, int M) {
    mfma_gemm_body<128, 256, false, false>(A, Wp, b, C, nullptr, M);
}
__global__ __launch_bounds__(256, 4) void mfma_ep1(const unsigned short* A, const unsigned short* Wp,
                                                   const float* b, unsigned short* C, const int* gidx, int M) {
    mfma_gemm_body<128, 128, true, true>(A, Wp, b, C, gidx, M);
}
__global__ __launch_bounds__(256, 4) void mfma_ep2(const unsigned short* A, const unsigned short* Wp,
                                                   const float* b, float* C, int M) {
    mfma_gemm_body<64, 128, false, false>(A, Wp, b, C, nullptr, M);
}

// ---------------- fp32 tiled GEMM (conv layers): C = dinv .* (A@W) ----------
template<int NC, int KTOT>
__device__ __forceinline__ void gemm_body(
    const float* __restrict__ A, const float* __restrict__ W,
    float* __restrict__ C, const float* __restrict__ dinv, int M)
{
    constexpr int KB = 32;
    __shared__ float As[KB][68];
    __shared__ float Ws[KB][64];

    int t  = threadIdx.x;
    int m0 = blockIdx.x * 64;
    int c0 = blockIdx.y * 64;
    int tx = t & 15, ty = t >> 4;

    float acc[4][4];
    #pragma unroll
    for (int r = 0; r < 4; ++r)
        #pragma unroll
        for (int c = 0; c < 4; ++c) acc[r][c] = 0.f;

    for (int k0 = 0; k0 < KTOT; k0 += KB) {
        #pragma unroll
        for (int j = 0; j < 2; ++j) {
            int idx = t + j * 256;
            int row = idx >> 3, kf = idx & 7;
            int gr  = m0 + row;
            float4 v = make_float4(0.f, 0.f, 0.f, 0.f);
            if (gr < M) v = *(const float4*)&A[(size_t)gr * KTOT + k0 + kf * 4];
            As[kf * 4 + 0][row] = v.x; As[kf * 4 + 1][row] = v.y;
            As[kf * 4 + 2][row] = v.z; As[kf * 4 + 3][row] = v.w;
        }
        #pragma unroll
        for (int j = 0; j < 2; ++j) {
            int idx = t + j * 256;
            int kk = idx >> 4, cf = idx & 15;
            *(float4*)&Ws[kk][cf * 4] = *(const float4*)&W[(size_t)(k0 + kk) * NC + c0 + cf * 4];
        }
        __syncthreads();

        #pragma unroll
        for (int kk = 0; kk < KB; ++kk) {
            float4 a4 = *(const float4*)&As[kk][ty * 4];
            float4 w4 = *(const float4*)&Ws[kk][tx * 4];
            acc[0][0] += a4.x * w4.x; acc[0][1] += a4.x * w4.y;
            acc[0][2] += a4.x * w4.z; acc[0][3] += a4.x * w4.w;
            acc[1][0] += a4.y * w4.x; acc[1][1] += a4.y * w4.y;
            acc[1][2] += a4.y * w4.z; acc[1][3] += a4.y * w4.w;
            acc[2][0] += a4.z * w4.x; acc[2][1] += a4.z * w4.y;
            acc[2][2] += a4.z * w4.z; acc[2][3] += a4.z * w4.w;
            acc[3][0] += a4.w * w4.x; acc[3][1] += a4.w * w4.y;
            acc[3][2] += a4.w * w4.z; acc[3][3] += a4.w * w4.w;
        }
        __syncthreads();
    }

    #pragma unroll
    for (int r = 0; r < 4; ++r) {
        int gr = m0 + ty * 4 + r;
        if (gr < M) {
            float s = dinv[gr];
            float4 v;
            v.x = acc[r][0] * s; v.y = acc[r][1] * s;
            v.z = acc[r][2] * s; v.w = acc[r][3] * s;
            *(float4*)&C[(size_t)gr * NC + c0 + tx * 4] = v;
        }
    }
}

__global__ __launch_bounds__(256, 4) void gemm_conv0(const float* A, const float* W, float* C, const float* dinv, int M) {
    gemm_body<64, 128>(A, W, C, dinv, M);
}
__global__ __launch_bounds__(256, 4) void gemm_conv1(const float* A, const float* W, float* C, const float* dinv, int M) {
    gemm_body<64, 64>(A, W, C, dinv, M);
}
__global__ __launch_bounds__(256, 4) void gemm_conv2(const float* A, const float* W, float* C, const float* dinv, int M) {
    gemm_body<64, 64>(A, W, C, dinv, M);
}

// ---------------- CSR aggregation: one wave per node, lane = feature --------
template<bool RESIDUAL, bool OUT_BF16>
__device__ __forceinline__ void agg_body(
    const float* __restrict__ y, const int* __restrict__ row_ptr, const int* __restrict__ col,
    const float* __restrict__ dinv, const float* __restrict__ bias,
    const float* __restrict__ hprev, void* __restrict__ hout)
{
    int v = blockIdx.x * 4 + (threadIdx.x >> 6);
    int lane = threadIdx.x & 63;
    if (v >= N_NODES) return;
    float acc = y[(size_t)v * 64 + lane];           // self loop
    int s = row_ptr[v], e = row_ptr[v + 1];
    int i = s;
    for (; i + 3 < e; i += 4) {
        int u0 = col[i], u1 = col[i + 1], u2 = col[i + 2], u3 = col[i + 3];
        float f0 = y[(size_t)u0 * 64 + lane];
        float f1 = y[(size_t)u1 * 64 + lane];
        float f2 = y[(size_t)u2 * 64 + lane];
        float f3 = y[(size_t)u3 * 64 + lane];
        acc += f0 + f1 + f2 + f3;
    }
    for (; i < e; ++i) acc += y[(size_t)col[i] * 64 + lane];
    float val = fmaxf(dinv[v] * acc + bias[lane], 0.f);
    size_t o = (size_t)v * 64 + lane;
    if (RESIDUAL) val += hprev[o];
    if (OUT_BF16) ((unsigned short*)hout)[o] = f2bf(val);
    else          ((float*)hout)[o] = val;
}

__global__ __launch_bounds__(256) void agg0_kernel(const float* y, const int* rp, const int* col,
                                                   const float* dinv, const float* b, float* h) {
    agg_body<false, false>(y, rp, col, dinv, b, nullptr, h);
}
__global__ __launch_bounds__(256) void agg1_kernel(const float* y, const int* rp, const int* col,
                                                   const float* dinv, const float* b, float* h) {
    agg_body<true, false>(y, rp, col, dinv, b, h, h);   // in-place: wave owns its row
}
__global__ __launch_bounds__(256) void agg2_kernel(const float* y, const int* rp, const int* col,
                                                   const float* dinv, const float* b,
                                                   const float* hprev, unsigned short* hb) {
    agg_body<true, true>(y, rp, col, dinv, b, hprev, hb);
}

// ---------------- final edge layer: dot(e2[p], w3) + b3 -> sigmoid ----------
__global__ __launch_bounds__(256) void ep3_kernel(const float* __restrict__ e2, const float* __restrict__ w3,
                                                  const float* __restrict__ b3, float* __restrict__ out) {
    int p = blockIdx.x * 4 + (threadIdx.x >> 6);
    int lane = threadIdx.x & 63;
    if (p >= N_EL) return;
    float v = e2[(size_t)p * 64 + lane] * w3[lane];
    v += __shfl_xor(v, 32);
    v += __shfl_xor(v, 16);
    v += __shfl_xor(v, 8);
    v += __shfl_xor(v, 4);
    v += __shfl_xor(v, 2);
    v += __shfl_xor(v, 1);
    if (lane == 0) out[p] = 1.f / (1.f + expf(-(v + b3[0])));
}

extern "C" void kernel_launch(void* const* d_in, const int* in_sizes, int n_in,
                              void* d_out, int out_size, void* d_ws, size_t ws_size,
                              hipStream_t stream) {
    const float* x       = (const float*)d_in[0];
    const int*   ei      = (const int*)d_in[1];
    const int*   eli     = (const int*)d_in[2];
    const float* enc_w1  = (const float*)d_in[3];
    const float* enc_b1  = (const float*)d_in[4];
    const float* enc_w2  = (const float*)d_in[5];
    const float* enc_b2  = (const float*)d_in[6];
    const float* conv_w0 = (const float*)d_in[7];
    const float* conv_b0 = (const float*)d_in[8];
    const float* conv_w1 = (const float*)d_in[9];
    const float* conv_b1 = (const float*)d_in[10];
    const float* conv_w2 = (const float*)d_in[11];
    const float* conv_b2 = (const float*)d_in[12];
    const float* ep_w1   = (const float*)d_in[13];
    const float* ep_b1   = (const float*)d_in[14];
    const float* ep_w2   = (const float*)d_in[15];
    const float* ep_b2   = (const float*)d_in[16];
    const float* ep_w3   = (const float*)d_in[17];
    const float* ep_b3   = (const float*)d_in[18];
    float* out = (float*)d_out;

    // ---- workspace layout (float offsets; ~176 MB total) ----
    float* fws = (float*)d_ws;
    unsigned short* h1b  = (unsigned short*)fws;                 // [100k x 256] bf16 = 12.8M floats
    float* h128          = fws + 12800000;                       // [100k x 128] f32  = 12.8M floats
    unsigned short* e1b  = (unsigned short*)h128;                // alias: [200k x 128] bf16 (h128 dead after conv0)
    float* yb            = fws + 25600000;                       // [100k x 64] f32 = 6.4M
    float* h64           = fws + 32000000;                       // [100k x 64] f32 = 6.4M
    float* e2            = yb;                                   // alias: [200k x 64] f32 = yb+h64 (dead after agg2)
    unsigned short* h64b = (unsigned short*)(fws + 38400000);    // [100k x 64] bf16 = 3.2M floats
    int*   col     = (int*)(fws + 41600000);                     // 1.6M
    int*   row_ptr = col + 1600000;                              // 100001 (padded)
    int*   cursor  = row_ptr + 100032;
    int*   cnt     = cursor + 100000;
    float* dinvp   = (float*)(cnt + 100000);
    int*   partial = (int*)(dinvp + 100000);                     // 256
    unsigned short* w2p  = (unsigned short*)(partial + 256);     // enc_w2 swizzled: 32768 us
    unsigned short* w1p  = w2p + 32768;                          // ep_w1: 16384 us
    unsigned short* wp2  = w1p + 16384;                          // ep_w2: 8192 us

    // ---- CSR build + weight swizzle ----
    hipMemsetAsync(cnt, 0, N_NODES * sizeof(int), stream);
    deg_kernel <<<(N_EDGES + 255) / 256, 256, 0, stream>>>(ei, cnt);
    wprep_kernel<256, 128><<<128, 256, 0, stream>>>(enc_w2, w2p);
    wprep_kernel<128, 128><<< 64, 256, 0, stream>>>(ep_w1,  w1p);
    wprep_kernel<128,  64><<< 32, 256, 0, stream>>>(ep_w2,  wp2);
    dinv_kernel<<<(N_NODES + 255) / 256, 256, 0, stream>>>(cnt, dinvp);
    scan1<<<SCAN_NB, 256, 0, stream>>>(cnt, partial);
    scan2<<<1, 256, 0, stream>>>(partial, row_ptr);
    scan3<<<SCAN_NB, 256, 0, stream>>>(cnt, partial, row_ptr, cursor);
    fill_kernel<<<2048, 256, 0, stream>>>(ei, cursor, col);

    const int GBN = (N_NODES + 63) / 64;   // 1563
    const int GBE = N_EL / 64;             // 3125

    // ---- encoder ----
    enc1_kernel<<<GBN, 256, 0, stream>>>(x, enc_w1, enc_b1, h1b);
    mfma_enc2<<<GBN, 256, 0, stream>>>(h1b, w2p, enc_b2, h128, N_NODES);

    // ---- GCN layer 0: 128 -> 64 ----
    gemm_conv0<<<dim3(GBN, 1), 256, 0, stream>>>(h128, conv_w0, yb, dinvp, N_NODES);
    agg0_kernel<<<(N_NODES + 3) / 4, 256, 0, stream>>>(yb, row_ptr, col, dinvp, conv_b0, h64);

    // ---- GCN layer 1: 64 -> 64, residual ----
    gemm_conv1<<<dim3(GBN, 1), 256, 0, stream>>>(h64, conv_w1, yb, dinvp, N_NODES);
    agg1_kernel<<<(N_NODES + 3) / 4, 256, 0, stream>>>(yb, row_ptr, col, dinvp, conv_b1, h64);

    // ---- GCN layer 2: 64 -> 64, residual, bf16 out for ep1 ----
    gemm_conv2<<<dim3(GBN, 1), 256, 0, stream>>>(h64, conv_w2, yb, dinvp, N_NODES);
    agg2_kernel<<<(N_NODES + 3) / 4, 256, 0, stream>>>(yb, row_ptr, col, dinvp, conv_b2, h64, h64b);

    // ---- edge predictor (bf16 MFMA) ----
    mfma_ep1<<<GBE, 256, 0, stream>>>(h64b, w1p, ep_b1, e1b, eli, N_EL);
    mfma_ep2<<<GBE, 256, 0, stream>>>(e1b, wp2, ep_b2, e2, N_EL);
    ep3_kernel<<<(N_EL + 3) / 4, 256, 0, stream>>>(e2, ep_w3, ep_b3, out);
}

// Round 6
// 627.508 us; speedup vs baseline: 17.3781x; 1.0645x over previous
//
#include <hip/hip_runtime.h>
#include <math.h>

// ---------------------------------------------------------------------------
// EmergencyGNNEnhanced: encoder (32->256->128) -> 3x GCN (->64) -> edge MLP.
// CSR built on-device each call. agg[v] = dinv[v]*(sum_{u->v} y[u] + y[v]).
//
// R6: aggregation traffic cut via dtype. agg FETCH was 202MB = 8 XCDs x 25.6MB
// fp32 y (random gather -> every XCD pulls the full array). y now fp16
// (rel 5e-4), h128 now bf16 (sole consumer conv0 -> becomes MFMA kernel).
// h64 residual chain stays fp32. MFMA layouts HW-verified (R5 passed):
//   A[m=lane&15][k=(lane>>4)*8+j], B[k=(lane>>4)*8+j][n=lane&15],
//   D col=lane&15, row=(lane>>4)*4+reg.
// ---------------------------------------------------------------------------

#define N_NODES 100000
#define N_EDGES 1600000
#define N_EL    200000
#define SCAN_NB 196          // ceil(100000/512)
#define FILL_WIN 12500       // N_NODES/8 dst window per XCD group

typedef __attribute__((ext_vector_type(8))) short short8_t;
typedef __attribute__((ext_vector_type(4))) float f32x4;

__device__ __forceinline__ unsigned short f2bf(float f) {
    unsigned u = __float_as_uint(f);
    unsigned r = u + 0x7FFFu + ((u >> 16) & 1u);   // RNE
    return (unsigned short)(r >> 16);
}

// ---------------- CSR build ----------------
__global__ __launch_bounds__(256) void deg_kernel(const int* __restrict__ ei, int* __restrict__ cnt) {
    int e = blockIdx.x * 256 + threadIdx.x;
    if (e < N_EDGES) atomicAdd(&cnt[ei[N_EDGES + e]], 1);
}

__global__ __launch_bounds__(256) void dinv_kernel(const int* __restrict__ cnt, float* __restrict__ dinv) {
    int i = blockIdx.x * 256 + threadIdx.x;
    if (i < N_NODES) dinv[i] = rsqrtf((float)(cnt[i] + 1));   // +1 self loop
}

__global__ __launch_bounds__(256) void scan1(const int* __restrict__ cnt, int* __restrict__ partial) {
    __shared__ int sm[256];
    int b = blockIdx.x, t = threadIdx.x;
    int base = b * 512;
    int v = 0;
    if (base + t < N_NODES)       v += cnt[base + t];
    if (base + 256 + t < N_NODES) v += cnt[base + 256 + t];
    sm[t] = v; __syncthreads();
    for (int s = 128; s > 0; s >>= 1) { if (t < s) sm[t] += sm[t + s]; __syncthreads(); }
    if (t == 0) partial[b] = sm[0];
}

__global__ __launch_bounds__(256) void scan2(int* __restrict__ partial, int* __restrict__ row_ptr) {
    __shared__ int sm[256];
    int t = threadIdx.x;
    int v = (t < SCAN_NB) ? partial[t] : 0;
    sm[t] = v; __syncthreads();
    for (int s = 1; s < 256; s <<= 1) {
        int add = (t >= s) ? sm[t - s] : 0;
        __syncthreads();
        sm[t] += add;
        __syncthreads();
    }
    if (t < SCAN_NB) partial[t] = sm[t] - v;          // exclusive
    if (t == 0) row_ptr[N_NODES] = N_EDGES;
}

__global__ __launch_bounds__(256) void scan3(const int* __restrict__ cnt, const int* __restrict__ partial,
                                             int* __restrict__ row_ptr, int* __restrict__ cursor) {
    __shared__ int sm[256];
    int b = blockIdx.x, t = threadIdx.x;
    int base = b * 512;
    int i0 = base + 2 * t, i1 = i0 + 1;
    int e0 = (i0 < N_NODES) ? cnt[i0] : 0;
    int e1 = (i1 < N_NODES) ? cnt[i1] : 0;
    int s2 = e0 + e1;
    sm[t] = s2; __syncthreads();
    for (int s = 1; s < 256; s <<= 1) {
        int add = (t >= s) ? sm[t - s] : 0;
        __syncthreads();
        sm[t] += add;
        __syncthreads();
    }
    int excl = sm[t] - s2 + partial[b];
    if (i0 < N_NODES) { row_ptr[i0] = excl;      cursor[i0] = excl; }
    if (i1 < N_NODES) { row_ptr[i1] = excl + e0; cursor[i1] = excl + e0; }
}

// Windowed fill (R4): dst-window per blockIdx%8 XCD group -> full-line writes.
__global__ __launch_bounds__(256) void fill_kernel(const int* __restrict__ ei, int* __restrict__ cursor,
                                                   int* __restrict__ col) {
    int w  = blockIdx.x & 7;
    int lo = w * FILL_WIN, hi = lo + FILL_WIN;
    int nb = gridDim.x >> 3;
    int bi = blockIdx.x >> 3;
    for (int e = bi * 256 + (int)threadIdx.x; e < N_EDGES; e += nb * 256) {
        int d = ei[N_EDGES + e];
        if (d >= lo && d < hi) {
            int p = atomicAdd(&cursor[d], 1);
            col[p] = ei[e];
        }
    }
}

// ---------------- enc1: weight-stationary 32->256, bf16 output ----------------
__global__ __launch_bounds__(256, 2) void enc1_kernel(
    const float* __restrict__ x, const float* __restrict__ W,
    const float* __restrict__ bias, unsigned short* __restrict__ C)
{
    __shared__ float Ws[32][256];
    __shared__ float xt[32][68];
    __shared__ float bs[256];

    int t  = threadIdx.x;
    int r0 = blockIdx.x * 64;

    #pragma unroll
    for (int j = 0; j < 8; ++j) {
        int idx = t + j * 256;
        int kk = idx >> 6, cf = idx & 63;
        *(float4*)&Ws[kk][cf * 4] = *(const float4*)&W[kk * 256 + cf * 4];
    }
    if (t < 64) *(float4*)&bs[t * 4] = *(const float4*)&bias[t * 4];

    #pragma unroll
    for (int j = 0; j < 2; ++j) {
        int fidx = t + j * 256;
        int row = fidx >> 3, kf = fidx & 7;
        int gr = r0 + row;
        float4 v = (gr < N_NODES) ? *(const float4*)&x[(size_t)gr * 32 + kf * 4]
                                  : make_float4(0.f, 0.f, 0.f, 0.f);
        xt[kf * 4 + 0][row] = v.x; xt[kf * 4 + 1][row] = v.y;
        xt[kf * 4 + 2][row] = v.z; xt[kf * 4 + 3][row] = v.w;
    }
    __syncthreads();

    int tx = t & 63, ty = t >> 6;
    float4 b4 = *(const float4*)&bs[tx * 4];
    float4 acc[16];
    #pragma unroll
    for (int r = 0; r < 16; ++r) acc[r] = b4;

    #pragma unroll 4
    for (int k = 0; k < 32; ++k) {
        float4 w4 = *(const float4*)&Ws[k][tx * 4];
        #pragma unroll
        for (int j = 0; j < 4; ++j) {
            float4 a4 = *(const float4*)&xt[k][ty * 16 + j * 4];
            acc[j * 4 + 0].x += a4.x * w4.x; acc[j * 4 + 0].y += a4.x * w4.y;
            acc[j * 4 + 0].z += a4.x * w4.z; acc[j * 4 + 0].w += a4.x * w4.w;
            acc[j * 4 + 1].x += a4.y * w4.x; acc[j * 4 + 1].y += a4.y * w4.y;
            acc[j * 4 + 1].z += a4.y * w4.z; acc[j * 4 + 1].w += a4.y * w4.w;
            acc[j * 4 + 2].x += a4.z * w4.x; acc[j * 4 + 2].y += a4.z * w4.y;
            acc[j * 4 + 2].z += a4.z * w4.z; acc[j * 4 + 2].w += a4.z * w4.w;
            acc[j * 4 + 3].x += a4.w * w4.x; acc[j * 4 + 3].y += a4.w * w4.y;
            acc[j * 4 + 3].z += a4.w * w4.z; acc[j * 4 + 3].w += a4.w * w4.w;
        }
    }

    #pragma unroll
    for (int r = 0; r < 16; ++r) {
        int gr = r0 + ty * 16 + r;
        if (gr < N_NODES) {
            float4 v = acc[r];
            unsigned p0 = (unsigned)f2bf(fmaxf(v.x, 0.f)) | ((unsigned)f2bf(fmaxf(v.y, 0.f)) << 16);
            unsigned p1 = (unsigned)f2bf(fmaxf(v.z, 0.f)) | ((unsigned)f2bf(fmaxf(v.w, 0.f)) << 16);
            *(uint2*)&C[(size_t)gr * 256 + tx * 4] = make_uint2(p0, p1);
        }
    }
}

// ---------------- weight swizzle: fp32 W[K][N] -> bf16 B-fragment order -----
template<int KTOT, int NTOT>
__global__ __launch_bounds__(256) void wprep_kernel(const float* __restrict__ W, unsigned short* __restrict__ Wp) {
    int flat = blockIdx.x * 256 + threadIdx.x;
    if (flat >= KTOT * NTOT) return;
    int j = flat & 7, lane = (flat >> 3) & 63, kstep = (flat >> 9) & 1;
    int rest = flat >> 10;
    int ntile = rest % (NTOT / 16), chunk = rest / (NTOT / 16);
    int k = chunk * 64 + kstep * 32 + (lane >> 4) * 8 + j;
    int n = ntile * 16 + (lane & 15);
    Wp[flat] = f2bf(W[(size_t)k * NTOT + n]);
}

// ---------------- bf16 MFMA GEMM ----------------
// 64 rows/block, 4 waves: wave = 16 rows x NTOT cols. K in 64-chunks.
// BIAS_RELU: C = relu(A@W + bias); else C = dinv .* (A@W).
// OUTT: 0=f32, 1=bf16, 2=f16.
template<int NTOT, int KTOT, bool GATHER, bool BIAS_RELU, int OUTT>
__device__ __forceinline__ void mfma_gemm_body(
    const unsigned short* __restrict__ A, const unsigned short* __restrict__ Wp,
    const float* __restrict__ bias, const float* __restrict__ dinv,
    void* __restrict__ Cout, const int* __restrict__ gidx, int M)
{
    constexpr int NT16 = NTOT / 16;
    constexpr int NCH  = KTOT / 64;
    __shared__ unsigned short As[64][72];
    __shared__ unsigned short Wls[NT16 * 1024];

    int t = threadIdx.x, wave = t >> 6, lane = t & 63;
    int m0 = blockIdx.x * 64;

    f32x4 acc[NT16];
    #pragma unroll
    for (int nt = 0; nt < NT16; ++nt) acc[nt] = (f32x4){0.f, 0.f, 0.f, 0.f};

    for (int ch = 0; ch < NCH; ++ch) {
        #pragma unroll
        for (int j = 0; j < 2; ++j) {
            int idx = t + j * 256;
            int row = idx >> 3, seg = idx & 7;
            int gr = m0 + row;
            uint4 v = make_uint4(0u, 0u, 0u, 0u);
            if (gr < M) {
                const unsigned short* src;
                if (GATHER) {
                    int node = (ch == 0) ? gidx[gr] : gidx[N_EL + gr];
                    src = A + (size_t)node * 64 + seg * 8;
                } else {
                    src = A + (size_t)gr * KTOT + ch * 64 + seg * 8;
                }
                v = *(const uint4*)src;
            }
            *(uint4*)&As[row][seg * 8] = v;
        }
        constexpr int WL16 = NT16 * 128;            // uint4 count
        #pragma unroll
        for (int j = 0; j < WL16 / 256; ++j) {
            int idx = t + j * 256;
            ((uint4*)Wls)[idx] = ((const uint4*)(Wp + (size_t)ch * NT16 * 1024))[idx];
        }
        __syncthreads();

        #pragma unroll
        for (int ks = 0; ks < 2; ++ks) {
            short8_t af = *(const short8_t*)&As[wave * 16 + (lane & 15)][ks * 32 + (lane >> 4) * 8];
            #pragma unroll
            for (int nt = 0; nt < NT16; ++nt) {
                short8_t bf = *(const short8_t*)&Wls[((nt * 2 + ks) * 64 + lane) * 8];
                acc[nt] = __builtin_amdgcn_mfma_f32_16x16x32_bf16(af, bf, acc[nt], 0, 0, 0);
            }
        }
        __syncthreads();
    }

    int cb = lane & 15, rq = lane >> 4;
    #pragma unroll
    for (int nt = 0; nt < NT16; ++nt) {
        int col = nt * 16 + cb;
        float bv = BIAS_RELU ? bias[col] : 0.f;
        #pragma unroll
        for (int r = 0; r < 4; ++r) {
            int gr = m0 + wave * 16 + rq * 4 + r;
            if (gr < M) {
                float val;
                if (BIAS_RELU) val = fmaxf(acc[nt][r] + bv, 0.f);
                else           val = acc[nt][r] * dinv[gr];
                size_t o = (size_t)gr * NTOT + col;
                if (OUTT == 1)      ((unsigned short*)Cout)[o] = f2bf(val);
                else if (OUTT == 2) ((_Float16*)Cout)[o] = (_Float16)val;
                else                ((float*)Cout)[o] = val;
            }
        }
    }
}

__global__ __launch_bounds__(256, 4) void mfma_enc2(const unsigned short* A, const unsigned short* Wp,
                                                    const float* b, unsigned short* C, int M) {
    mfma_gemm_body<128, 256, false, true, 1>(A, Wp, b, nullptr, C, nullptr, M);
}
__global__ __launch_bounds__(256, 4) void mfma_conv0(const unsigned short* A, const unsigned short* Wp,
                                                     const float* dinv, _Float16* C, int M) {
    mfma_gemm_body<64, 128, false, false, 2>(A, Wp, nullptr, dinv, C, nullptr, M);
}
__global__ __launch_bounds__(256, 4) void mfma_ep1(const unsigned short* A, const unsigned short* Wp,
                                                   const float* b, unsigned short* C, const int* gidx, int M) {
    mfma_gemm_body<128, 128, true, true, 1>(A, Wp, b, nullptr, C, gidx, M);
}
__global__ __launch_bounds__(256, 4) void mfma_ep2(const unsigned short* A, const unsigned short* Wp,
                                                   const float* b, float* C, int M) {
    mfma_gemm_body<64, 128, false, true, 0>(A, Wp, b, nullptr, C, nullptr, M);
}

// ---------------- fp32 tiled GEMM (conv1/2): y = f16(dinv .* (A@W)) ---------
template<int KTOT>
__device__ __forceinline__ void gemm_body(
    const float* __restrict__ A, const float* __restrict__ W,
    _Float16* __restrict__ C, const float* __restrict__ dinv, int M)
{
    constexpr int KB = 32;
    constexpr int NC = 64;
    __shared__ float As[KB][68];
    __shared__ float Ws[KB][64];

    int t  = threadIdx.x;
    int m0 = blockIdx.x * 64;
    int tx = t & 15, ty = t >> 4;

    float acc[4][4];
    #pragma unroll
    for (int r = 0; r < 4; ++r)
        #pragma unroll
        for (int c = 0; c < 4; ++c) acc[r][c] = 0.f;

    for (int k0 = 0; k0 < KTOT; k0 += KB) {
        #pragma unroll
        for (int j = 0; j < 2; ++j) {
            int idx = t + j * 256;
            int row = idx >> 3, kf = idx & 7;
            int gr  = m0 + row;
            float4 v = make_float4(0.f, 0.f, 0.f, 0.f);
            if (gr < M) v = *(const float4*)&A[(size_t)gr * KTOT + k0 + kf * 4];
            As[kf * 4 + 0][row] = v.x; As[kf * 4 + 1][row] = v.y;
            As[kf * 4 + 2][row] = v.z; As[kf * 4 + 3][row] = v.w;
        }
        #pragma unroll
        for (int j = 0; j < 2; ++j) {
            int idx = t + j * 256;
            int kk = idx >> 4, cf = idx & 15;
            *(float4*)&Ws[kk][cf * 4] = *(const float4*)&W[(size_t)(k0 + kk) * NC + cf * 4];
        }
        __syncthreads();

        #pragma unroll
        for (int kk = 0; kk < KB; ++kk) {
            float4 a4 = *(const float4*)&As[kk][ty * 4];
            float4 w4 = *(const float4*)&Ws[kk][tx * 4];
            acc[0][0] += a4.x * w4.x; acc[0][1] += a4.x * w4.y;
            acc[0][2] += a4.x * w4.z; acc[0][3] += a4.x * w4.w;
            acc[1][0] += a4.y * w4.x; acc[1][1] += a4.y * w4.y;
            acc[1][2] += a4.y * w4.z; acc[1][3] += a4.y * w4.w;
            acc[2][0] += a4.z * w4.x; acc[2][1] += a4.z * w4.y;
            acc[2][2] += a4.z * w4.z; acc[2][3] += a4.z * w4.w;
            acc[3][0] += a4.w * w4.x; acc[3][1] += a4.w * w4.y;
            acc[3][2] += a4.w * w4.z; acc[3][3] += a4.w * w4.w;
        }
        __syncthreads();
    }

    #pragma unroll
    for (int r = 0; r < 4; ++r) {
        int gr = m0 + ty * 4 + r;
        if (gr < M) {
            float s = dinv[gr];
            _Float16 tmp[4];
            tmp[0] = (_Float16)(acc[r][0] * s);
            tmp[1] = (_Float16)(acc[r][1] * s);
            tmp[2] = (_Float16)(acc[r][2] * s);
            tmp[3] = (_Float16)(acc[r][3] * s);
            *(uint2*)&C[(size_t)gr * NC + tx * 4] = *(uint2*)tmp;
        }
    }
}

__global__ __launch_bounds__(256, 4) void gemm_conv1(const float* A, const float* W, _Float16* C, const float* dinv, int M) {
    gemm_body<64>(A, W, C, dinv, M);
}
__global__ __launch_bounds__(256, 4) void gemm_conv2(const float* A, const float* W, _Float16* C, const float* dinv, int M) {
    gemm_body<64>(A, W, C, dinv, M);
}

// ---------------- CSR aggregation: one wave per node, lane = feature --------
// y is fp16 (halves the 8-XCD gather amplification traffic).
template<bool RESIDUAL, bool OUT_BF16>
__device__ __forceinline__ void agg_body(
    const _Float16* __restrict__ y, const int* __restrict__ row_ptr, const int* __restrict__ col,
    const float* __restrict__ dinv, const float* __restrict__ bias,
    const float* __restrict__ hprev, void* __restrict__ hout,
    unsigned short* __restrict__ hb)
{
    int v = blockIdx.x * 4 + (threadIdx.x >> 6);
    int lane = threadIdx.x & 63;
    if (v >= N_NODES) return;
    float acc = (float)y[(size_t)v * 64 + lane];    // self loop
    int s = row_ptr[v], e = row_ptr[v + 1];
    int i = s;
    for (; i + 3 < e; i += 4) {
        int u0 = col[i], u1 = col[i + 1], u2 = col[i + 2], u3 = col[i + 3];
        float f0 = (float)y[(size_t)u0 * 64 + lane];
        float f1 = (float)y[(size_t)u1 * 64 + lane];
        float f2 = (float)y[(size_t)u2 * 64 + lane];
        float f3 = (float)y[(size_t)u3 * 64 + lane];
        acc += f0 + f1 + f2 + f3;
    }
    for (; i < e; ++i) acc += (float)y[(size_t)col[i] * 64 + lane];
    float val = fmaxf(dinv[v] * acc + bias[lane], 0.f);
    size_t o = (size_t)v * 64 + lane;
    if (RESIDUAL) val += hprev[o];
    ((float*)hout)[o] = val;
    if (OUT_BF16) hb[o] = f2bf(val);
}

__global__ __launch_bounds__(256) void agg0_kernel(const _Float16* y, const int* rp, const int* col,
                                                   const float* dinv, const float* b, float* h) {
    agg_body<false, false>(y, rp, col, dinv, b, nullptr, h, nullptr);
}
__global__ __launch_bounds__(256) void agg1_kernel(const _Float16* y, const int* rp, const int* col,
                                                   const float* dinv, const float* b, float* h) {
    agg_body<true, false>(y, rp, col, dinv, b, h, h, nullptr);   // in-place: wave owns its row
}
__global__ __launch_bounds__(256) void agg2_kernel(const _Float16* y, const int* rp, const int* col,
                                                   const float* dinv, const float* b,
                                                   const float* hprev, float* h, unsigned short* hb) {
    agg_body<true, true>(y, rp, col, dinv, b, hprev, h, hb);
}

// ---------------- final edge layer: dot(e2[p], w3) + b3 -> sigmoid ----------
__global__ __launch_bounds__(256) void ep3_kernel(const float* __restrict__ e2, const float* __restrict__ w3,
                                                  const float* __restrict__ b3, float* __restrict__ out) {
    int p = blockIdx.x * 4 + (threadIdx.x >> 6);
    int lane = threadIdx.x & 63;
    if (p >= N_EL) return;
    float v = e2[(size_t)p * 64 + lane] * w3[lane];
    v += __shfl_xor(v, 32);
    v += __shfl_xor(v, 16);
    v += __shfl_xor(v, 8);
    v += __shfl_xor(v, 4);
    v += __shfl_xor(v, 2);
    v += __shfl_xor(v, 1);
    if (lane == 0) out[p] = 1.f / (1.f + expf(-(v + b3[0])));
}

extern "C" void kernel_launch(void* const* d_in, const int* in_sizes, int n_in,
                              void* d_out, int out_size, void* d_ws, size_t ws_size,
                              hipStream_t stream) {
    const float* x       = (const float*)d_in[0];
    const int*   ei      = (const int*)d_in[1];
    const int*   eli     = (const int*)d_in[2];
    const float* enc_w1  = (const float*)d_in[3];
    const float* enc_b1  = (const float*)d_in[4];
    const float* enc_w2  = (const float*)d_in[5];
    const float* enc_b2  = (const float*)d_in[6];
    const float* conv_w0 = (const float*)d_in[7];
    const float* conv_b0 = (const float*)d_in[8];
    const float* conv_w1 = (const float*)d_in[9];
    const float* conv_b1 = (const float*)d_in[10];
    const float* conv_w2 = (const float*)d_in[11];
    const float* conv_b2 = (const float*)d_in[12];
    const float* ep_w1   = (const float*)d_in[13];
    const float* ep_b1   = (const float*)d_in[14];
    const float* ep_w2   = (const float*)d_in[15];
    const float* ep_b2   = (const float*)d_in[16];
    const float* ep_w3   = (const float*)d_in[17];
    const float* ep_b3   = (const float*)d_in[18];
    float* out = (float*)d_out;

    // ---- workspace layout (float offsets; ~162 MB) ----
    float* fws = (float*)d_ws;
    unsigned short* h1b  = (unsigned short*)fws;                 // bf16 [100k,256] = 12.8M f
    float* e2            = fws;                                  // alias: f32 [200k,64] (h1b dead after enc2)
    unsigned short* e1b  = (unsigned short*)(fws + 12800000);    // bf16 [200k,128] = 12.8M f
    unsigned short* h128b= e1b;                                  // alias: bf16 [100k,128] (first 6.4M f; dead before ep1)
    _Float16* yb         = (_Float16*)(fws + 25600000);          // f16 [100k,64] = 3.2M f
    float* h64           = fws + 28800000;                       // f32 [100k,64] = 6.4M f
    unsigned short* h64b = (unsigned short*)(fws + 35200000);    // bf16 [100k,64] = 3.2M f
    int*   col     = (int*)(fws + 38400000);                     // 1.6M i
    int*   row_ptr = col + 1600000;                              // 100001 (padded)
    int*   cursor  = row_ptr + 100032;
    int*   cnt     = cursor + 100000;
    float* dinvp   = (float*)(cnt + 100000);
    int*   partial = (int*)(dinvp + 100000);                     // 256
    unsigned short* w2p = (unsigned short*)(partial + 256);      // enc_w2: 32768 us
    unsigned short* w0p = w2p + 32768;                           // conv_w0: 8192 us
    unsigned short* w1p = w0p + 8192;                            // ep_w1: 16384 us
    unsigned short* wp2 = w1p + 16384;                           // ep_w2: 8192 us

    // ---- CSR build + weight swizzle ----
    hipMemsetAsync(cnt, 0, N_NODES * sizeof(int), stream);
    deg_kernel <<<(N_EDGES + 255) / 256, 256, 0, stream>>>(ei, cnt);
    wprep_kernel<256, 128><<<128, 256, 0, stream>>>(enc_w2,  w2p);
    wprep_kernel<128,  64><<< 32, 256, 0, stream>>>(conv_w0, w0p);
    wprep_kernel<128, 128><<< 64, 256, 0, stream>>>(ep_w1,   w1p);
    wprep_kernel<128,  64><<< 32, 256, 0, stream>>>(ep_w2,   wp2);
    dinv_kernel<<<(N_NODES + 255) / 256, 256, 0, stream>>>(cnt, dinvp);
    scan1<<<SCAN_NB, 256, 0, stream>>>(cnt, partial);
    scan2<<<1, 256, 0, stream>>>(partial, row_ptr);
    scan3<<<SCAN_NB, 256, 0, stream>>>(cnt, partial, row_ptr, cursor);
    fill_kernel<<<2048, 256, 0, stream>>>(ei, cursor, col);

    const int GBN = (N_NODES + 63) / 64;   // 1563
    const int GBE = N_EL / 64;             // 3125

    // ---- encoder ----
    enc1_kernel<<<GBN, 256, 0, stream>>>(x, enc_w1, enc_b1, h1b);
    mfma_enc2<<<GBN, 256, 0, stream>>>(h1b, w2p, enc_b2, h128b, N_NODES);

    // ---- GCN layer 0: 128 -> 64 (MFMA, bf16 in, f16 y out) ----
    mfma_conv0<<<GBN, 256, 0, stream>>>(h128b, w0p, dinvp, yb, N_NODES);
    agg0_kernel<<<(N_NODES + 3) / 4, 256, 0, stream>>>(yb, row_ptr, col, dinvp, conv_b0, h64);

    // ---- GCN layer 1: 64 -> 64, residual ----
    gemm_conv1<<<GBN, 256, 0, stream>>>(h64, conv_w1, yb, dinvp, N_NODES);
    agg1_kernel<<<(N_NODES + 3) / 4, 256, 0, stream>>>(yb, row_ptr, col, dinvp, conv_b1, h64);

    // ---- GCN layer 2: 64 -> 64, residual, bf16 copy for ep1 ----
    gemm_conv2<<<GBN, 256, 0, stream>>>(h64, conv_w2, yb, dinvp, N_NODES);
    agg2_kernel<<<(N_NODES + 3) / 4, 256, 0, stream>>>(yb, row_ptr, col, dinvp, conv_b2, h64, h64, h64b);

    // ---- edge predictor (bf16 MFMA) ----
    mfma_ep1<<<GBE, 256, 0, stream>>>(h64b, w1p, ep_b1, e1b, eli, N_EL);
    mfma_ep2<<<GBE, 256, 0, stream>>>(e1b, wp2, ep_b2, e2, N_EL);
    ep3_kernel<<<(N_EL + 3) / 4, 256, 0, stream>>>(e2, ep_w3, ep_b3, out);
}

// Round 7
// 536.734 us; speedup vs baseline: 20.3171x; 1.1691x over previous
//
#include <hip/hip_runtime.h>
#include <math.h>

// ---------------------------------------------------------------------------
// EmergencyGNNEnhanced: encoder (32->256->128) -> 3x GCN (->64) -> edge MLP.
// CSR built on-device each call. agg[v] = dinv[v]*(sum_{u->v} y[u] + y[v]).
//
// R7: (a) fill/deg use nontemporal ei loads -- R6 showed the 6.4MB/group ei
// stream thrashed the XCD L2 and evicted partial col lines (WRITE 73MB vs
// 6.4MB logical); nt loads don't allocate, col lines fill before writeback.
// (b) agg: 2 nodes/wave, 2 packed-fp16 features/lane -> half the VMEM insts
// per edge, 2x independent gather streams (latency-bound kernel).
// (c) ep3 fused into ep2 epilogue (w3-dot + sigmoid via shfl) -- kills the
// 51MB e2 write + re-read. MFMA layouts HW-verified (R5/R6 passed).
// ---------------------------------------------------------------------------

#define N_NODES 100000
#define N_EDGES 1600000
#define N_EL    200000
#define SCAN_NB 196          // ceil(100000/512)
#define FILL_WIN 12500       // N_NODES/8 dst window per XCD group

typedef __attribute__((ext_vector_type(8))) short short8_t;
typedef __attribute__((ext_vector_type(4))) float f32x4;

__device__ __forceinline__ unsigned short f2bf(float f) {
    unsigned u = __float_as_uint(f);
    unsigned r = u + 0x7FFFu + ((u >> 16) & 1u);   // RNE
    return (unsigned short)(r >> 16);
}

__device__ __forceinline__ float2 up16(unsigned u) {
    union { unsigned v; _Float16 h[2]; } c; c.v = u;
    return make_float2((float)c.h[0], (float)c.h[1]);
}

// ---------------- CSR build ----------------
__global__ __launch_bounds__(256) void deg_kernel(const int* __restrict__ ei, int* __restrict__ cnt) {
    int e = blockIdx.x * 256 + threadIdx.x;
    if (e < N_EDGES) {
        int d = __builtin_nontemporal_load(ei + N_EDGES + e);
        atomicAdd(&cnt[d], 1);
    }
}

__global__ __launch_bounds__(256) void dinv_kernel(const int* __restrict__ cnt, float* __restrict__ dinv) {
    int i = blockIdx.x * 256 + threadIdx.x;
    if (i < N_NODES) dinv[i] = rsqrtf((float)(cnt[i] + 1));   // +1 self loop
}

__global__ __launch_bounds__(256) void scan1(const int* __restrict__ cnt, int* __restrict__ partial) {
    __shared__ int sm[256];
    int b = blockIdx.x, t = threadIdx.x;
    int base = b * 512;
    int v = 0;
    if (base + t < N_NODES)       v += cnt[base + t];
    if (base + 256 + t < N_NODES) v += cnt[base + 256 + t];
    sm[t] = v; __syncthreads();
    for (int s = 128; s > 0; s >>= 1) { if (t < s) sm[t] += sm[t + s]; __syncthreads(); }
    if (t == 0) partial[b] = sm[0];
}

__global__ __launch_bounds__(256) void scan2(int* __restrict__ partial, int* __restrict__ row_ptr) {
    __shared__ int sm[256];
    int t = threadIdx.x;
    int v = (t < SCAN_NB) ? partial[t] : 0;
    sm[t] = v; __syncthreads();
    for (int s = 1; s < 256; s <<= 1) {
        int add = (t >= s) ? sm[t - s] : 0;
        __syncthreads();
        sm[t] += add;
        __syncthreads();
    }
    if (t < SCAN_NB) partial[t] = sm[t] - v;          // exclusive
    if (t == 0) row_ptr[N_NODES] = N_EDGES;
}

__global__ __launch_bounds__(256) void scan3(const int* __restrict__ cnt, const int* __restrict__ partial,
                                             int* __restrict__ row_ptr, int* __restrict__ cursor) {
    __shared__ int sm[256];
    int b = blockIdx.x, t = threadIdx.x;
    int base = b * 512;
    int i0 = base + 2 * t, i1 = i0 + 1;
    int e0 = (i0 < N_NODES) ? cnt[i0] : 0;
    int e1 = (i1 < N_NODES) ? cnt[i1] : 0;
    int s2 = e0 + e1;
    sm[t] = s2; __syncthreads();
    for (int s = 1; s < 256; s <<= 1) {
        int add = (t >= s) ? sm[t - s] : 0;
        __syncthreads();
        sm[t] += add;
        __syncthreads();
    }
    int excl = sm[t] - s2 + partial[b];
    if (i0 < N_NODES) { row_ptr[i0] = excl;      cursor[i0] = excl; }
    if (i1 < N_NODES) { row_ptr[i1] = excl + e0; cursor[i1] = excl + e0; }
}

// Windowed fill (R4) + nt ei loads (R7): col lines stay in the XCD L2 until
// full; ei stream bypasses. Correct under any block->XCD mapping.
__global__ __launch_bounds__(256) void fill_kernel(const int* __restrict__ ei, int* __restrict__ cursor,
                                                   int* __restrict__ col) {
    int w  = blockIdx.x & 7;
    int lo = w * FILL_WIN, hi = lo + FILL_WIN;
    int nb = gridDim.x >> 3;
    int bi = blockIdx.x >> 3;
    for (int e = bi * 256 + (int)threadIdx.x; e < N_EDGES; e += nb * 256) {
        int d = __builtin_nontemporal_load(ei + N_EDGES + e);
        if (d >= lo && d < hi) {
            int p = atomicAdd(&cursor[d], 1);
            col[p] = __builtin_nontemporal_load(ei + e);
        }
    }
}

// ---------------- enc1: weight-stationary 32->256, bf16 output ----------------
__global__ __launch_bounds__(256, 2) void enc1_kernel(
    const float* __restrict__ x, const float* __restrict__ W,
    const float* __restrict__ bias, unsigned short* __restrict__ C)
{
    __shared__ float Ws[32][256];
    __shared__ float xt[32][68];
    __shared__ float bs[256];

    int t  = threadIdx.x;
    int r0 = blockIdx.x * 64;

    #pragma unroll
    for (int j = 0; j < 8; ++j) {
        int idx = t + j * 256;
        int kk = idx >> 6, cf = idx & 63;
        *(float4*)&Ws[kk][cf * 4] = *(const float4*)&W[kk * 256 + cf * 4];
    }
    if (t < 64) *(float4*)&bs[t * 4] = *(const float4*)&bias[t * 4];

    #pragma unroll
    for (int j = 0; j < 2; ++j) {
        int fidx = t + j * 256;
        int row = fidx >> 3, kf = fidx & 7;
        int gr = r0 + row;
        float4 v = (gr < N_NODES) ? *(const float4*)&x[(size_t)gr * 32 + kf * 4]
                                  : make_float4(0.f, 0.f, 0.f, 0.f);
        xt[kf * 4 + 0][row] = v.x; xt[kf * 4 + 1][row] = v.y;
        xt[kf * 4 + 2][row] = v.z; xt[kf * 4 + 3][row] = v.w;
    }
    __syncthreads();

    int tx = t & 63, ty = t >> 6;
    float4 b4 = *(const float4*)&bs[tx * 4];
    float4 acc[16];
    #pragma unroll
    for (int r = 0; r < 16; ++r) acc[r] = b4;

    #pragma unroll 4
    for (int k = 0; k < 32; ++k) {
        float4 w4 = *(const float4*)&Ws[k][tx * 4];
        #pragma unroll
        for (int j = 0; j < 4; ++j) {
            float4 a4 = *(const float4*)&xt[k][ty * 16 + j * 4];
            acc[j * 4 + 0].x += a4.x * w4.x; acc[j * 4 + 0].y += a4.x * w4.y;
            acc[j * 4 + 0].z += a4.x * w4.z; acc[j * 4 + 0].w += a4.x * w4.w;
            acc[j * 4 + 1].x += a4.y * w4.x; acc[j * 4 + 1].y += a4.y * w4.y;
            acc[j * 4 + 1].z += a4.y * w4.z; acc[j * 4 + 1].w += a4.y * w4.w;
            acc[j * 4 + 2].x += a4.z * w4.x; acc[j * 4 + 2].y += a4.z * w4.y;
            acc[j * 4 + 2].z += a4.z * w4.z; acc[j * 4 + 2].w += a4.z * w4.w;
            acc[j * 4 + 3].x += a4.w * w4.x; acc[j * 4 + 3].y += a4.w * w4.y;
            acc[j * 4 + 3].z += a4.w * w4.z; acc[j * 4 + 3].w += a4.w * w4.w;
        }
    }

    #pragma unroll
    for (int r = 0; r < 16; ++r) {
        int gr = r0 + ty * 16 + r;
        if (gr < N_NODES) {
            float4 v = acc[r];
            unsigned p0 = (unsigned)f2bf(fmaxf(v.x, 0.f)) | ((unsigned)f2bf(fmaxf(v.y, 0.f)) << 16);
            unsigned p1 = (unsigned)f2bf(fmaxf(v.z, 0.f)) | ((unsigned)f2bf(fmaxf(v.w, 0.f)) << 16);
            *(uint2*)&C[(size_t)gr * 256 + tx * 4] = make_uint2(p0, p1);
        }
    }
}

// ---------------- weight swizzle: fp32 W[K][N] -> bf16 B-fragment order -----
template<int KTOT, int NTOT>
__global__ __launch_bounds__(256) void wprep_kernel(const float* __restrict__ W, unsigned short* __restrict__ Wp) {
    int flat = blockIdx.x * 256 + threadIdx.x;
    if (flat >= KTOT * NTOT) return;
    int j = flat & 7, lane = (flat >> 3) & 63, kstep = (flat >> 9) & 1;
    int rest = flat >> 10;
    int ntile = rest % (NTOT / 16), chunk = rest / (NTOT / 16);
    int k = chunk * 64 + kstep * 32 + (lane >> 4) * 8 + j;
    int n = ntile * 16 + (lane & 15);
    Wp[flat] = f2bf(W[(size_t)k * NTOT + n]);
}

// ---------------- bf16 MFMA GEMM ----------------
// 64 rows/block, 4 waves: wave = 16 rows x NTOT cols. K in 64-chunks.
// BIAS_RELU: C = relu(A@W + bias); else C = dinv .* (A@W).
// OUTT: 0=f32, 1=bf16, 2=f16.
template<int NTOT, int KTOT, bool GATHER, bool BIAS_RELU, int OUTT>
__device__ __forceinline__ void mfma_gemm_body(
    const unsigned short* __restrict__ A, const unsigned short* __restrict__ Wp,
    const float* __restrict__ bias, const float* __restrict__ dinv,
    void* __restrict__ Cout, const int* __restrict__ gidx, int M)
{
    constexpr int NT16 = NTOT / 16;
    constexpr int NCH  = KTOT / 64;
    __shared__ unsigned short As[64][72];
    __shared__ unsigned short Wls[NT16 * 1024];

    int t = threadIdx.x, wave = t >> 6, lane = t & 63;
    int m0 = blockIdx.x * 64;

    f32x4 acc[NT16];
    #pragma unroll
    for (int nt = 0; nt < NT16; ++nt) acc[nt] = (f32x4){0.f, 0.f, 0.f, 0.f};

    for (int ch = 0; ch < NCH; ++ch) {
        #pragma unroll
        for (int j = 0; j < 2; ++j) {
            int idx = t + j * 256;
            int row = idx >> 3, seg = idx & 7;
            int gr = m0 + row;
            uint4 v = make_uint4(0u, 0u, 0u, 0u);
            if (gr < M) {
                const unsigned short* src;
                if (GATHER) {
                    int node = (ch == 0) ? gidx[gr] : gidx[N_EL + gr];
                    src = A + (size_t)node * 64 + seg * 8;
                } else {
                    src = A + (size_t)gr * KTOT + ch * 64 + seg * 8;
                }
                v = *(const uint4*)src;
            }
            *(uint4*)&As[row][seg * 8] = v;
        }
        constexpr int WL16 = NT16 * 128;            // uint4 count
        #pragma unroll
        for (int j = 0; j < WL16 / 256; ++j) {
            int idx = t + j * 256;
            ((uint4*)Wls)[idx] = ((const uint4*)(Wp + (size_t)ch * NT16 * 1024))[idx];
        }
        __syncthreads();

        #pragma unroll
        for (int ks = 0; ks < 2; ++ks) {
            short8_t af = *(const short8_t*)&As[wave * 16 + (lane & 15)][ks * 32 + (lane >> 4) * 8];
            #pragma unroll
            for (int nt = 0; nt < NT16; ++nt) {
                short8_t bf = *(const short8_t*)&Wls[((nt * 2 + ks) * 64 + lane) * 8];
                acc[nt] = __builtin_amdgcn_mfma_f32_16x16x32_bf16(af, bf, acc[nt], 0, 0, 0);
            }
        }
        __syncthreads();
    }

    int cb = lane & 15, rq = lane >> 4;
    #pragma unroll
    for (int nt = 0; nt < NT16; ++nt) {
        int col = nt * 16 + cb;
        float bv = BIAS_RELU ? bias[col] : 0.f;
        #pragma unroll
        for (int r = 0; r < 4; ++r) {
            int gr = m0 + wave * 16 + rq * 4 + r;
            if (gr < M) {
                float val;
                if (BIAS_RELU) val = fmaxf(acc[nt][r] + bv, 0.f);
                else           val = acc[nt][r] * dinv[gr];
                size_t o = (size_t)gr * NTOT + col;
                if (OUTT == 1)      ((unsigned short*)Cout)[o] = f2bf(val);
                else if (OUTT == 2) ((_Float16*)Cout)[o] = (_Float16)val;
                else                ((float*)Cout)[o] = val;
            }
        }
    }
}

__global__ __launch_bounds__(256, 4) void mfma_enc2(const unsigned short* A, const unsigned short* Wp,
                                                    const float* b, unsigned short* C, int M) {
    mfma_gemm_body<128, 256, false, true, 1>(A, Wp, b, nullptr, C, nullptr, M);
}
__global__ __launch_bounds__(256, 4) void mfma_conv0(const unsigned short* A, const unsigned short* Wp,
                                                     const float* dinv, _Float16* C, int M) {
    mfma_gemm_body<64, 128, false, false, 2>(A, Wp, nullptr, dinv, C, nullptr, M);
}
__global__ __launch_bounds__(256, 4) void mfma_ep1(const unsigned short* A, const unsigned short* Wp,
                                                   const float* b, unsigned short* C, const int* gidx, int M) {
    mfma_gemm_body<128, 128, true, true, 1>(A, Wp, b, nullptr, C, gidx, M);
}

// ---------------- ep2 fused with ep3: sigmoid(relu(e1@W2+b2) . w3 + b3) -----
// Same MFMA main loop (NTOT=64, KTOT=128); epilogue dots each row with w3
// via per-lane partials + 16-lane shfl reduce, writes out[gr] directly.
__global__ __launch_bounds__(256, 4) void mfma_ep2f(
    const unsigned short* __restrict__ A, const unsigned short* __restrict__ Wp,
    const float* __restrict__ b2, const float* __restrict__ w3,
    const float* __restrict__ b3, float* __restrict__ out, int M)
{
    constexpr int NT16 = 4;
    __shared__ unsigned short As[64][72];
    __shared__ unsigned short Wls[NT16 * 1024];

    int t = threadIdx.x, wave = t >> 6, lane = t & 63;
    int m0 = blockIdx.x * 64;

    f32x4 acc[NT16];
    #pragma unroll
    for (int nt = 0; nt < NT16; ++nt) acc[nt] = (f32x4){0.f, 0.f, 0.f, 0.f};

    for (int ch = 0; ch < 2; ++ch) {
        #pragma unroll
        for (int j = 0; j < 2; ++j) {
            int idx = t + j * 256;
            int row = idx >> 3, seg = idx & 7;
            int gr = m0 + row;
            uint4 v = make_uint4(0u, 0u, 0u, 0u);
            if (gr < M) v = *(const uint4*)(A + (size_t)gr * 128 + ch * 64 + seg * 8);
            *(uint4*)&As[row][seg * 8] = v;
        }
        #pragma unroll
        for (int j = 0; j < 2; ++j) {
            int idx = t + j * 256;
            ((uint4*)Wls)[idx] = ((const uint4*)(Wp + (size_t)ch * NT16 * 1024))[idx];
        }
        __syncthreads();

        #pragma unroll
        for (int ks = 0; ks < 2; ++ks) {
            short8_t af = *(const short8_t*)&As[wave * 16 + (lane & 15)][ks * 32 + (lane >> 4) * 8];
            #pragma unroll
            for (int nt = 0; nt < NT16; ++nt) {
                short8_t bf = *(const short8_t*)&Wls[((nt * 2 + ks) * 64 + lane) * 8];
                acc[nt] = __builtin_amdgcn_mfma_f32_16x16x32_bf16(af, bf, acc[nt], 0, 0, 0);
            }
        }
        __syncthreads();
    }

    int cb = lane & 15, rq = lane >> 4;
    float s0 = 0.f, s1 = 0.f, s2 = 0.f, s3 = 0.f;
    #pragma unroll
    for (int nt = 0; nt < NT16; ++nt) {
        int col = nt * 16 + cb;
        float bv = b2[col], wv = w3[col];
        s0 += fmaxf(acc[nt][0] + bv, 0.f) * wv;
        s1 += fmaxf(acc[nt][1] + bv, 0.f) * wv;
        s2 += fmaxf(acc[nt][2] + bv, 0.f) * wv;
        s3 += fmaxf(acc[nt][3] + bv, 0.f) * wv;
    }
    #pragma unroll
    for (int off = 1; off < 16; off <<= 1) {
        s0 += __shfl_xor(s0, off);
        s1 += __shfl_xor(s1, off);
        s2 += __shfl_xor(s2, off);
        s3 += __shfl_xor(s3, off);
    }
    if (cb == 0) {
        int gr = m0 + wave * 16 + rq * 4;
        if (gr + 3 < M) {
            float bb = b3[0];
            float4 o;
            o.x = 1.f / (1.f + expf(-(s0 + bb)));
            o.y = 1.f / (1.f + expf(-(s1 + bb)));
            o.z = 1.f / (1.f + expf(-(s2 + bb)));
            o.w = 1.f / (1.f + expf(-(s3 + bb)));
            *(float4*)&out[gr] = o;
        }
    }
}

// ---------------- fp32 tiled GEMM (conv1/2): y = f16(dinv .* (A@W)) ---------
template<int KTOT>
__device__ __forceinline__ void gemm_body(
    const float* __restrict__ A, const float* __restrict__ W,
    _Float16* __restrict__ C, const float* __restrict__ dinv, int M)
{
    constexpr int KB = 32;
    constexpr int NC = 64;
    __shared__ float As[KB][68];
    __shared__ float Ws[KB][64];

    int t  = threadIdx.x;
    int m0 = blockIdx.x * 64;
    int tx = t & 15, ty = t >> 4;

    float acc[4][4];
    #pragma unroll
    for (int r = 0; r < 4; ++r)
        #pragma unroll
        for (int c = 0; c < 4; ++c) acc[r][c] = 0.f;

    for (int k0 = 0; k0 < KTOT; k0 += KB) {
        #pragma unroll
        for (int j = 0; j < 2; ++j) {
            int idx = t + j * 256;
            int row = idx >> 3, kf = idx & 7;
            int gr  = m0 + row;
            float4 v = make_float4(0.f, 0.f, 0.f, 0.f);
            if (gr < M) v = *(const float4*)&A[(size_t)gr * KTOT + k0 + kf * 4];
            As[kf * 4 + 0][row] = v.x; As[kf * 4 + 1][row] = v.y;
            As[kf * 4 + 2][row] = v.z; As[kf * 4 + 3][row] = v.w;
        }
        #pragma unroll
        for (int j = 0; j < 2; ++j) {
            int idx = t + j * 256;
            int kk = idx >> 4, cf = idx & 15;
            *(float4*)&Ws[kk][cf * 4] = *(const float4*)&W[(size_t)(k0 + kk) * NC + cf * 4];
        }
        __syncthreads();

        #pragma unroll
        for (int kk = 0; kk < KB; ++kk) {
            float4 a4 = *(const float4*)&As[kk][ty * 4];
            float4 w4 = *(const float4*)&Ws[kk][tx * 4];
            acc[0][0] += a4.x * w4.x; acc[0][1] += a4.x * w4.y;
            acc[0][2] += a4.x * w4.z; acc[0][3] += a4.x * w4.w;
            acc[1][0] += a4.y * w4.x; acc[1][1] += a4.y * w4.y;
            acc[1][2] += a4.y * w4.z; acc[1][3] += a4.y * w4.w;
            acc[2][0] += a4.z * w4.x; acc[2][1] += a4.z * w4.y;
            acc[2][2] += a4.z * w4.z; acc[2][3] += a4.z * w4.w;
            acc[3][0] += a4.w * w4.x; acc[3][1] += a4.w * w4.y;
            acc[3][2] += a4.w * w4.z; acc[3][3] += a4.w * w4.w;
        }
        __syncthreads();
    }

    #pragma unroll
    for (int r = 0; r < 4; ++r) {
        int gr = m0 + ty * 4 + r;
        if (gr < M) {
            float s = dinv[gr];
            _Float16 tmp[4];
            tmp[0] = (_Float16)(acc[r][0] * s);
            tmp[1] = (_Float16)(acc[r][1] * s);
            tmp[2] = (_Float16)(acc[r][2] * s);
            tmp[3] = (_Float16)(acc[r][3] * s);
            *(uint2*)&C[(size_t)gr * NC + tx * 4] = *(uint2*)tmp;
        }
    }
}

__global__ __launch_bounds__(256, 4) void gemm_conv1(const float* A, const float* W, _Float16* C, const float* dinv, int M) {
    gemm_body<64>(A, W, C, dinv, M);
}
__global__ __launch_bounds__(256, 4) void gemm_conv2(const float* A, const float* W, _Float16* C, const float* dinv, int M) {
    gemm_body<64>(A, W, C, dinv, M);
}

// ---------------- CSR aggregation ----------------
// R7: 2 nodes per wave (32 lanes each), 2 packed-fp16 features per lane
// (uint gather) -> half the VMEM instructions per edge, 2 independent
// neighbor streams per wave. Writes float2 / packed-bf16-uint per lane.
// OUTM: 0 = f32 only, 1 = f32 in-place residual, 2 = bf16 only (+f32 hprev).
template<bool RESIDUAL, int OUTM>
__device__ __forceinline__ void agg_body(
    const unsigned* __restrict__ y32, const int* __restrict__ row_ptr, const int* __restrict__ col,
    const float* __restrict__ dinv, const float* __restrict__ bias,
    const float* __restrict__ hprev, float* __restrict__ hout,
    unsigned* __restrict__ hb32)
{
    int v  = blockIdx.x * 8 + (threadIdx.x >> 5);
    int sl = threadIdx.x & 31;
    if (v >= N_NODES) return;

    float2 a = up16(y32[(size_t)v * 32 + sl]);     // self loop
    float a0 = a.x, a1 = a.y;
    int s = row_ptr[v], e = row_ptr[v + 1];
    int i = s;
    for (; i + 3 < e; i += 4) {
        int u0 = col[i], u1 = col[i + 1], u2 = col[i + 2], u3 = col[i + 3];
        float2 f0 = up16(y32[(size_t)u0 * 32 + sl]);
        float2 f1 = up16(y32[(size_t)u1 * 32 + sl]);
        float2 f2 = up16(y32[(size_t)u2 * 32 + sl]);
        float2 f3 = up16(y32[(size_t)u3 * 32 + sl]);
        a0 += (f0.x + f1.x) + (f2.x + f3.x);
        a1 += (f0.y + f1.y) + (f2.y + f3.y);
    }
    for (; i < e; ++i) {
        float2 f = up16(y32[(size_t)col[i] * 32 + sl]);
        a0 += f.x; a1 += f.y;
    }
    float dv = dinv[v];
    float2 b = *(const float2*)&bias[sl * 2];
    float v0 = fmaxf(dv * a0 + b.x, 0.f);
    float v1 = fmaxf(dv * a1 + b.y, 0.f);
    size_t o = (size_t)v * 32 + sl;
    if (RESIDUAL) {
        float2 hp = *(const float2*)&hprev[o * 2];
        v0 += hp.x; v1 += hp.y;
    }
    if (OUTM == 2) {
        hb32[o] = (unsigned)f2bf(v0) | ((unsigned)f2bf(v1) << 16);
    } else {
        *(float2*)&hout[o * 2] = make_float2(v0, v1);
    }
}

__global__ __launch_bounds__(256) void agg0_kernel(const unsigned* y, const int* rp, const int* col,
                                                   const float* dinv, const float* b, float* h) {
    agg_body<false, 0>(y, rp, col, dinv, b, nullptr, h, nullptr);
}
__global__ __launch_bounds__(256) void agg1_kernel(const unsigned* y, const int* rp, const int* col,
                                                   const float* dinv, const float* b, float* h) {
    agg_body<true, 1>(y, rp, col, dinv, b, h, h, nullptr);   // in-place: half-wave owns its row
}
__global__ __launch_bounds__(256) void agg2_kernel(const unsigned* y, const int* rp, const int* col,
                                                   const float* dinv, const float* b,
                                                   const float* hprev, unsigned* hb) {
    agg_body<true, 2>(y, rp, col, dinv, b, hprev, nullptr, hb);
}

extern "C" void kernel_launch(void* const* d_in, const int* in_sizes, int n_in,
                              void* d_out, int out_size, void* d_ws, size_t ws_size,
                              hipStream_t stream) {
    const float* x       = (const float*)d_in[0];
    const int*   ei      = (const int*)d_in[1];
    const int*   eli     = (const int*)d_in[2];
    const float* enc_w1  = (const float*)d_in[3];
    const float* enc_b1  = (const float*)d_in[4];
    const float* enc_w2  = (const float*)d_in[5];
    const float* enc_b2  = (const float*)d_in[6];
    const float* conv_w0 = (const float*)d_in[7];
    const float* conv_b0 = (const float*)d_in[8];
    const float* conv_w1 = (const float*)d_in[9];
    const float* conv_b1 = (const float*)d_in[10];
    const float* conv_w2 = (const float*)d_in[11];
    const float* conv_b2 = (const float*)d_in[12];
    const float* ep_w1   = (const float*)d_in[13];
    const float* ep_b1   = (const float*)d_in[14];
    const float* ep_w2   = (const float*)d_in[15];
    const float* ep_b2   = (const float*)d_in[16];
    const float* ep_w3   = (const float*)d_in[17];
    const float* ep_b3   = (const float*)d_in[18];
    float* out = (float*)d_out;

    // ---- workspace layout (float offsets) ----
    float* fws = (float*)d_ws;
    unsigned short* h1b  = (unsigned short*)fws;                 // bf16 [100k,256] = 12.8M f
    unsigned short* e1b  = (unsigned short*)(fws + 12800000);    // bf16 [200k,128] = 12.8M f
    unsigned short* h128b= e1b;                                  // alias: bf16 [100k,128] (dead before ep1)
    _Float16* yb         = (_Float16*)(fws + 25600000);          // f16 [100k,64] = 3.2M f
    float* h64           = fws + 28800000;                       // f32 [100k,64] = 6.4M f
    unsigned short* h64b = (unsigned short*)(fws + 35200000);    // bf16 [100k,64] = 3.2M f
    int*   col     = (int*)(fws + 38400000);                     // 1.6M i
    int*   row_ptr = col + 1600000;                              // 100001 (padded)
    int*   cursor  = row_ptr + 100032;
    int*   cnt     = cursor + 100000;
    float* dinvp   = (float*)(cnt + 100000);
    int*   partial = (int*)(dinvp + 100000);                     // 256
    unsigned short* w2p = (unsigned short*)(partial + 256);      // enc_w2: 32768 us
    unsigned short* w0p = w2p + 32768;                           // conv_w0: 8192 us
    unsigned short* w1p = w0p + 8192;                            // ep_w1: 16384 us
    unsigned short* wp2 = w1p + 16384;                           // ep_w2: 8192 us

    // ---- CSR build + weight swizzle ----
    hipMemsetAsync(cnt, 0, N_NODES * sizeof(int), stream);
    deg_kernel <<<(N_EDGES + 255) / 256, 256, 0, stream>>>(ei, cnt);
    wprep_kernel<256, 128><<<128, 256, 0, stream>>>(enc_w2,  w2p);
    wprep_kernel<128,  64><<< 32, 256, 0, stream>>>(conv_w0, w0p);
    wprep_kernel<128, 128><<< 64, 256, 0, stream>>>(ep_w1,   w1p);
    wprep_kernel<128,  64><<< 32, 256, 0, stream>>>(ep_w2,   wp2);
    dinv_kernel<<<(N_NODES + 255) / 256, 256, 0, stream>>>(cnt, dinvp);
    scan1<<<SCAN_NB, 256, 0, stream>>>(cnt, partial);
    scan2<<<1, 256, 0, stream>>>(partial, row_ptr);
    scan3<<<SCAN_NB, 256, 0, stream>>>(cnt, partial, row_ptr, cursor);
    fill_kernel<<<2048, 256, 0, stream>>>(ei, cursor, col);

    const int GBN = (N_NODES + 63) / 64;   // 1563
    const int GBE = N_EL / 64;             // 3125
    const int GBA = (N_NODES + 7) / 8;     // 12500

    // ---- encoder ----
    enc1_kernel<<<GBN, 256, 0, stream>>>(x, enc_w1, enc_b1, h1b);
    mfma_enc2<<<GBN, 256, 0, stream>>>(h1b, w2p, enc_b2, h128b, N_NODES);

    // ---- GCN layer 0: 128 -> 64 (MFMA, bf16 in, f16 y out) ----
    mfma_conv0<<<GBN, 256, 0, stream>>>(h128b, w0p, dinvp, yb, N_NODES);
    agg0_kernel<<<GBA, 256, 0, stream>>>((const unsigned*)yb, row_ptr, col, dinvp, conv_b0, h64);

    // ---- GCN layer 1: 64 -> 64, residual ----
    gemm_conv1<<<GBN, 256, 0, stream>>>(h64, conv_w1, yb, dinvp, N_NODES);
    agg1_kernel<<<GBA, 256, 0, stream>>>((const unsigned*)yb, row_ptr, col, dinvp, conv_b1, h64);

    // ---- GCN layer 2: 64 -> 64, residual, bf16 out for ep1 ----
    gemm_conv2<<<GBN, 256, 0, stream>>>(h64, conv_w2, yb, dinvp, N_NODES);
    agg2_kernel<<<GBA, 256, 0, stream>>>((const unsigned*)yb, row_ptr, col, dinvp, conv_b2, h64, (unsigned*)h64b);

    // ---- edge predictor (bf16 MFMA; ep2+ep3 fused) ----
    mfma_ep1<<<GBE, 256, 0, stream>>>(h64b, w1p, ep_b1, e1b, eli, N_EL);
    mfma_ep2f<<<GBE, 256, 0, stream>>>(e1b, wp2, ep_b2, ep_w3, ep_b3, out, N_EL);
}